// Round 1
// baseline (1054.496 us; speedup 1.0000x reference)
//
#include <hip/hip_runtime.h>
#include <hip/hip_bf16.h>

#define B_ 32
#define N_ 96
#define D_ 64
#define L_ 5
#define EP_ 768
#define BE_ 24576          // B*EP
#define NN_ 9216           // N*N
#define BNN_ 294912        // B*N*N
#define EPS_ 1e-5f
#define INV_NN (1.0f/9216.0f)

typedef unsigned short u16;
typedef unsigned int u32;

__device__ __forceinline__ float bflo(u32 r){ return __uint_as_float(r << 16); }
__device__ __forceinline__ float bfhi(u32 r){ return __uint_as_float(r & 0xffff0000u); }
__device__ __forceinline__ u32 f2bf(float f){
  u32 u = __float_as_uint(f);
  return (u + 0x7fffu + ((u >> 16) & 1u)) >> 16;   // RNE
}
__device__ __forceinline__ u32 pack2(float lo, float hi){
  return f2bf(lo) | (f2bf(hi) << 16);
}

// ---------------- scatter: build packed A (last-write-wins via priority) ----------------
__global__ void k_scatter(const int* __restrict__ ei, const int* __restrict__ ea,
                          int* __restrict__ A)
{
  int e = blockIdx.x * 256 + threadIdx.x;
  if (e >= BE_) return;
  int a = ei[e], bnode = ei[BE_ + e];
  int g = a / N_;
  int u = a % N_;
  int v = bnode % N_;
  int lab = ea[e] & 7;
  int base = g * NN_;
  // pass 1 (A[g,u,v]=ea) has priority e+1; pass 2 (A[g,v,u]=ea) priority BE+e+1.
  atomicMax(&A[base + u * N_ + v], ((e + 1) << 3) | lab);
  atomicMax(&A[base + v * N_ + u], ((BE_ + e + 1) << 3) | lab);
}

// ---------------- W init: W[b,q,d] = h_u + h_v + edge_emb[label] ----------------
__launch_bounds__(256)
__global__ void k_winit(const int* __restrict__ x, const int* __restrict__ A,
                        const float* __restrict__ nemb, const float* __restrict__ eemb,
                        float* __restrict__ W)
{
  int gid = blockIdx.x * 256 + threadIdx.x;      // over BNN_*64
  int d = gid & 63;
  int p = gid >> 6;
  int b = p / NN_;
  int rem = p % NN_;
  int u = rem / N_;
  int v = rem % N_;
  int xu = x[b * N_ + u], xv = x[b * N_ + v];
  int pk = A[p];
  int lab = pk ? (pk & 7) : 5;
  W[gid] = nemb[xu * 64 + d] + nemb[xv * 64 + d] + eemb[lab * 64 + d];
}

// ---------------- h1 / g2 GEMM: per 64-pair tile, outputs in [b][e][pair] bf16 ----------------
__launch_bounds__(256)
__global__ void k_h1g2(const float* __restrict__ W,
                       const float* __restrict__ W1l, const float* __restrict__ b1l,
                       const float* __restrict__ W2l, const float* __restrict__ b2l,
                       const int* __restrict__ A,
                       u16* __restrict__ h1, u16* __restrict__ g2,
                       const float* __restrict__ stp,
                       const float* __restrict__ gml, const float* __restrict__ btl,
                       int use_norm)
{
  __shared__ float At[64][68];    // [d][q]
  __shared__ float W1s[64][68];   // [d][e]
  __shared__ float W2s[64][68];
  const int tid = threadIdx.x;
  const int b = blockIdx.x / 144;
  const int qbase = (blockIdx.x % 144) * 64;

  const int d = tid & 63;
  float scale = 1.f, shift = 0.f;
  if (use_norm) {
    float S1 = stp[(b * 64 + d) * 2], S2 = stp[(b * 64 + d) * 2 + 1];
    float mu = S1 * INV_NN;
    float var = fmaf(S2, INV_NN, -mu * mu);
    float rsig = rsqrtf(var + EPS_);
    scale = gml[d] * rsig;
    shift = fmaf(-mu, scale, btl[d]);
  }
  const float* Wb = W + (size_t)(b * NN_ + qbase) * 64;
  #pragma unroll
  for (int k = 0; k < 16; k++) {
    int idx = k * 256 + tid;
    W1s[idx >> 6][idx & 63] = W1l[idx];
    W2s[idx >> 6][idx & 63] = W2l[idx];
    float w = Wb[idx];                     // idx = q*64 + d, d == tid&63
    if (use_norm) w = fmaxf(fmaf(w, scale, shift), 0.f);
    At[idx & 63][idx >> 6] = w;
  }
  __syncthreads();

  const int tx = tid & 15, ty = tid >> 4;
  const int q0 = ty * 4, e0 = tx * 4;
  float acc1[4][4] = {}; float acc2[4][4] = {};
  for (int dd = 0; dd < 64; dd++) {
    const float4 a  = *(const float4*)&At[dd][q0];
    const float4 u1 = *(const float4*)&W1s[dd][e0];
    const float4 u2 = *(const float4*)&W2s[dd][e0];
    const float av[4]  = {a.x, a.y, a.z, a.w};
    const float u1v[4] = {u1.x, u1.y, u1.z, u1.w};
    const float u2v[4] = {u2.x, u2.y, u2.z, u2.w};
    #pragma unroll
    for (int i = 0; i < 4; i++)
      #pragma unroll
      for (int j = 0; j < 4; j++) {
        acc1[i][j] = fmaf(av[i], u1v[j], acc1[i][j]);
        acc2[i][j] = fmaf(av[i], u2v[j], acc2[i][j]);
      }
  }
  __syncthreads();
  float bb1[4], bb2[4];
  #pragma unroll
  for (int j = 0; j < 4; j++) { bb1[j] = b1l[e0 + j]; bb2[j] = b2l[e0 + j]; }
  #pragma unroll
  for (int i = 0; i < 4; i++)
    #pragma unroll
    for (int j = 0; j < 4; j++) {
      At[e0 + j][q0 + i]  = fmaxf(acc1[i][j] + bb1[j], 0.f);   // h1 staged [e][q]
      W1s[e0 + j][q0 + i] = fmaxf(acc2[i][j] + bb2[j], 0.f);   // h2 staged [e][q]
    }
  __syncthreads();
  const int abase = b * NN_ + qbase;
  #pragma unroll
  for (int k = 0; k < 8; k++) {
    int idx2 = (k * 256 + tid) * 2;
    int e = idx2 >> 6, q = idx2 & 63;
    u32 ph = pack2(At[e][q], At[e][q + 1]);
    *(u32*)(h1 + (size_t)(b * 64 + e) * NN_ + qbase + q) = ph;
    float a0 = A[abase + q]     ? 1.f : 0.f;
    float a1 = A[abase + q + 1] ? 1.f : 0.f;
    u32 pg = pack2(W1s[e][q] * a0, W1s[e][q + 1] * a1);
    *(u32*)(g2 + (size_t)(b * 64 + e) * NN_ + qbase + q) = pg;
  }
}

// ---------------- per-(b,d) slice 96x96x96 GEMM: M_d = H1_d @ G2_d ----------------
__launch_bounds__(256)
__global__ void k_einsum(const u16* __restrict__ h1, const u16* __restrict__ g2,
                         u16* __restrict__ M)
{
  __shared__ u16 H1s[96 * 98];
  __shared__ u16 G2s[96 * 98];
  const int tid = threadIdx.x;
  const int bd = blockIdx.x;                 // b*64 + d
  const u16* h1p = h1 + (size_t)bd * NN_;
  const u16* g2p = g2 + (size_t)bd * NN_;
  #pragma unroll
  for (int k = 0; k < 9; k++) {
    int ii = k * 1024 + tid * 4;
    int r = ii / 96, c = ii % 96;
    uint2 rh = *(const uint2*)(h1p + ii);
    uint2 rg = *(const uint2*)(g2p + ii);
    int la = r * 98 + c;
    *(u32*)&H1s[la] = rh.x; *(u32*)&H1s[la + 2] = rh.y;
    *(u32*)&G2s[la] = rg.x; *(u32*)&G2s[la + 2] = rg.y;
  }
  __syncthreads();
  const int tx = tid & 15, ty = tid >> 4;
  const int u0 = ty * 6, v0 = tx * 6;
  float acc[6][6] = {};
  for (int w = 0; w < 96; ++w) {
    float av[6], bv[6];
    #pragma unroll
    for (int i = 0; i < 6; i++)
      av[i] = __uint_as_float(((u32)H1s[(u0 + i) * 98 + w]) << 16);
    #pragma unroll
    for (int jj = 0; jj < 3; jj++) {
      u32 raw = *(const u32*)&G2s[w * 98 + v0 + jj * 2];
      bv[2 * jj]     = bflo(raw);
      bv[2 * jj + 1] = bfhi(raw);
    }
    #pragma unroll
    for (int i = 0; i < 6; i++)
      #pragma unroll
      for (int j = 0; j < 6; j++)
        acc[i][j] = fmaf(av[i], bv[j], acc[i][j]);
  }
  __syncthreads();
  #pragma unroll
  for (int i = 0; i < 6; i++)
    #pragma unroll
    for (int jj = 0; jj < 3; jj++)
      *(u32*)&H1s[(u0 + i) * 98 + v0 + jj * 2] = pack2(acc[i][2 * jj], acc[i][2 * jj + 1]);
  __syncthreads();
  u16* Mp = M + (size_t)bd * NN_;
  #pragma unroll
  for (int k = 0; k < 9; k++) {
    int ii = k * 1024 + tid * 4;
    int r = ii / 96, c = ii % 96;
    int la = r * 98 + c;
    uint2 o; o.x = *(u32*)&H1s[la]; o.y = *(u32*)&H1s[la + 2];
    *(uint2*)(Mp + ii) = o;
  }
}

// ---------------- update: Wnew = res + M@Wm + bm; accumulate stats ----------------
__launch_bounds__(256)
__global__ void k_update(const u16* __restrict__ M,
                         const float* __restrict__ Wml, const float* __restrict__ bml,
                         float* __restrict__ W,
                         const float* __restrict__ stp,
                         const float* __restrict__ gml, const float* __restrict__ btl,
                         float* __restrict__ sto, int use_norm)
{
  __shared__ float Ms[64][68];    // [d][q]
  __shared__ float Wms[64][68];   // [d][e]
  __shared__ float red1[4][64];
  __shared__ float red2[4][64];
  const int tid = threadIdx.x;
  const int b = blockIdx.x / 144;
  const int qbase = (blockIdx.x % 144) * 64;
  #pragma unroll
  for (int k = 0; k < 16; k++) {
    int idx = k * 256 + tid;
    Wms[idx >> 6][idx & 63] = Wml[idx];
  }
  #pragma unroll
  for (int k = 0; k < 8; k++) {
    int idx2 = (k * 256 + tid) * 2;
    int dd = idx2 >> 6, q = idx2 & 63;
    u32 raw = *(const u32*)(M + (size_t)(b * 64 + dd) * NN_ + qbase + q);
    Ms[dd][q]     = bflo(raw);
    Ms[dd][q + 1] = bfhi(raw);
  }
  __syncthreads();
  const int tx = tid & 15, ty = tid >> 4;
  const int e0 = tx * 4, q0 = ty * 4;
  float acc[4][4] = {};
  for (int dd = 0; dd < 64; ++dd) {
    const float4 a  = *(const float4*)&Ms[dd][q0];
    const float4 wv = *(const float4*)&Wms[dd][e0];
    const float av[4] = {a.x, a.y, a.z, a.w};
    const float wvv[4] = {wv.x, wv.y, wv.z, wv.w};
    #pragma unroll
    for (int i = 0; i < 4; i++)
      #pragma unroll
      for (int j = 0; j < 4; j++)
        acc[i][j] = fmaf(av[i], wvv[j], acc[i][j]);
  }
  float scl[4], shf[4], bmv[4];
  #pragma unroll
  for (int j = 0; j < 4; j++) {
    int e = e0 + j;
    bmv[j] = bml[e];
    scl[j] = 1.f; shf[j] = 0.f;
    if (use_norm) {
      float S1 = stp[(b * 64 + e) * 2], S2 = stp[(b * 64 + e) * 2 + 1];
      float mu = S1 * INV_NN;
      float var = fmaf(S2, INV_NN, -mu * mu);
      float rsig = rsqrtf(var + EPS_);
      scl[j] = gml[e] * rsig;
      shf[j] = fmaf(-mu, scl[j], btl[e]);
    }
  }
  float s1[4] = {0, 0, 0, 0}, s2[4] = {0, 0, 0, 0};
  #pragma unroll
  for (int i = 0; i < 4; i++) {
    float* Wp = W + ((size_t)(b * NN_ + qbase + q0 + i)) * 64 + e0;
    float4 wo = *(const float4*)Wp;
    float wov[4] = {wo.x, wo.y, wo.z, wo.w};
    float out[4];
    #pragma unroll
    for (int j = 0; j < 4; j++) {
      float res = use_norm ? fmaxf(fmaf(wov[j], scl[j], shf[j]), 0.f) : wov[j];
      float val = acc[i][j] + bmv[j] + res;
      out[j] = val;
      s1[j] += val;
      s2[j] = fmaf(val, val, s2[j]);
    }
    float4 ov = {out[0], out[1], out[2], out[3]};
    *(float4*)Wp = ov;
  }
  #pragma unroll
  for (int j = 0; j < 4; j++) {
    s1[j] += __shfl_xor(s1[j], 16, 64);
    s1[j] += __shfl_xor(s1[j], 32, 64);
    s2[j] += __shfl_xor(s2[j], 16, 64);
    s2[j] += __shfl_xor(s2[j], 32, 64);
  }
  const int lane = tid & 63, wid = tid >> 6;
  if (lane < 16) {
    #pragma unroll
    for (int j = 0; j < 4; j++) {
      red1[wid][lane * 4 + j] = s1[j];
      red2[wid][lane * 4 + j] = s2[j];
    }
  }
  __syncthreads();
  if (tid < 64) {
    float t = red1[0][tid] + red1[1][tid] + red1[2][tid] + red1[3][tid];
    atomicAdd(&sto[(b * 64 + tid) * 2], t);
  } else if (tid < 128) {
    int e = tid - 64;
    float t = red2[0][e] + red2[1][e] + red2[2][e] + red2[3][e];
    atomicAdd(&sto[(b * 64 + e) * 2 + 1], t);
  }
}

// ---------------- pooling ----------------
__launch_bounds__(256)
__global__ void k_pool(const float* __restrict__ W,
                       const float* __restrict__ st,
                       const float* __restrict__ gml, const float* __restrict__ btl,
                       const float* __restrict__ pw, const float* __restrict__ pb,
                       float* __restrict__ out)
{
  const int b = blockIdx.x / 24;
  const int chunk = blockIdx.x % 24;
  const int tid = threadIdx.x;
  const int e = tid & 63;
  float S1 = st[(b * 64 + e) * 2], S2 = st[(b * 64 + e) * 2 + 1];
  float mu = S1 * INV_NN;
  float var = fmaf(S2, INV_NN, -mu * mu);
  float rsig = rsqrtf(var + EPS_);
  float scl = gml[e] * rsig;
  float shf = fmaf(-mu, scl, btl[e]);
  float pwv = pw[e];
  const float* base = W + (size_t)b * NN_ * 64 + chunk * 24576;
  float s = 0.f;
  for (int k = 0; k < 96; k++) {
    float w = base[k * 256 + tid];
    s += fmaxf(fmaf(w, scl, shf), 0.f) * pwv;
  }
  for (int o = 32; o; o >>= 1) s += __shfl_down(s, o, 64);
  __shared__ float rs[4];
  if ((tid & 63) == 0) rs[tid >> 6] = s;
  __syncthreads();
  if (tid == 0) {
    float t = rs[0] + rs[1] + rs[2] + rs[3];
    if (chunk == 0) t += pb[0];
    atomicAdd(&out[b], t);
  }
}

extern "C" void kernel_launch(void* const* d_in, const int* in_sizes, int n_in,
                              void* d_out, int out_size, void* d_ws, size_t ws_size,
                              hipStream_t stream) {
  const int*   x    = (const int*)d_in[0];
  const int*   ei   = (const int*)d_in[1];
  const int*   ea   = (const int*)d_in[2];
  const float* nemb = (const float*)d_in[3];
  const float* eemb = (const float*)d_in[4];
  const float* W1   = (const float*)d_in[5];
  const float* b1   = (const float*)d_in[6];
  const float* W2   = (const float*)d_in[7];
  const float* b2   = (const float*)d_in[8];
  const float* Wm   = (const float*)d_in[9];
  const float* bm   = (const float*)d_in[10];
  const float* gm   = (const float*)d_in[11];
  const float* bt   = (const float*)d_in[12];
  const float* pw   = (const float*)d_in[13];
  const float* pb   = (const float*)d_in[14];

  char* ws = (char*)d_ws;
  const size_t OFF_A  = 0;                    // int[BNN_]          1,179,648 B
  const size_t OFF_W  = 1179648;              // f32[BNN_*64]      75,497,472 B
  const size_t OFF_H1 = 76677120;             // bf16[BNN_*64]     37,748,736 B
  const size_t OFF_G2 = 114425856;            // bf16[BNN_*64]
  const size_t OFF_M  = 152174592;            // bf16[BNN_*64]
  const size_t OFF_ST = 189923328;            // f32[5][32][64][2]    163,840 B
  const size_t NEED   = OFF_ST + 163840;
  if (ws_size < NEED) return;                 // insufficient scratch -> fail loudly (zeros out)

  int*   A     = (int*)(ws + OFF_A);
  float* W     = (float*)(ws + OFF_W);
  u16*   h1    = (u16*)(ws + OFF_H1);
  u16*   g2    = (u16*)(ws + OFF_G2);
  u16*   M     = (u16*)(ws + OFF_M);
  float* stats = (float*)(ws + OFF_ST);
  float* out   = (float*)d_out;

  hipMemsetAsync(A, 0, 1179648, stream);
  hipMemsetAsync(stats, 0, 163840, stream);
  hipMemsetAsync(out, 0, 32 * sizeof(float), stream);

  k_scatter<<<96, 256, 0, stream>>>(ei, ea, A);
  k_winit<<<73728, 256, 0, stream>>>(x, A, nemb, eemb, W);

  for (int l = 0; l < L_; l++) {
    const float* stp = l ? stats + (size_t)(l - 1) * 4096 : stats;
    const float* gml = l ? gm + (l - 1) * 64 : gm;
    const float* btl = l ? bt + (l - 1) * 64 : bt;
    float* sto = stats + (size_t)l * 4096;
    k_h1g2<<<4608, 256, 0, stream>>>(W, W1 + l * 4096, b1 + l * 64,
                                     W2 + l * 4096, b2 + l * 64, A, h1, g2,
                                     stp, gml, btl, l);
    k_einsum<<<2048, 256, 0, stream>>>(h1, g2, M);
    k_update<<<4608, 256, 0, stream>>>(M, Wm + l * 4096, bm + l * 64, W,
                                       stp, gml, btl, sto, l);
  }
  k_pool<<<768, 256, 0, stream>>>(W, stats + 4 * 4096, gm + 4 * 64, bt + 4 * 64,
                                  pw, pb, out);
}

// Round 2
// 775.171 us; speedup vs baseline: 1.3603x; 1.3603x over previous
//
#include <hip/hip_runtime.h>
#include <hip/hip_bf16.h>

#define B_ 32
#define N_ 96
#define D_ 64
#define L_ 5
#define BE_ 24576
#define NN_ 9216
#define BNN_ 294912
#define EPS_ 1e-5f
#define INV_NN (1.0f/9216.0f)

typedef unsigned short u16;
typedef unsigned int u32;
typedef __attribute__((ext_vector_type(8))) short bf16x8;
typedef __attribute__((ext_vector_type(4))) float f32x4;

__device__ __forceinline__ u32 f2bf(float f){
  u32 u = __float_as_uint(f);
  return (u + 0x7fffu + ((u >> 16) & 1u)) >> 16;   // RNE
}

// ---------------- scatter: build packed A (last-write-wins via priority) ----------------
__global__ void k_scatter(const int* __restrict__ ei, const int* __restrict__ ea,
                          int* __restrict__ A)
{
  int e = blockIdx.x * 256 + threadIdx.x;
  if (e >= BE_) return;
  int a = ei[e], bnode = ei[BE_ + e];
  int g = a / N_;
  int u = a % N_;
  int v = bnode % N_;
  int lab = ea[e] & 7;
  int base = g * NN_;
  atomicMax(&A[base + u * N_ + v], ((e + 1) << 3) | lab);
  atomicMax(&A[base + v * N_ + u], ((BE_ + e + 1) << 3) | lab);
}

// ---------------- W init ----------------
__launch_bounds__(256)
__global__ void k_winit(const int* __restrict__ x, const int* __restrict__ A,
                        const float* __restrict__ nemb, const float* __restrict__ eemb,
                        float* __restrict__ W)
{
  int gid = blockIdx.x * 256 + threadIdx.x;      // over BNN_*64
  int d = gid & 63;
  int p = gid >> 6;
  int b = p / NN_;
  int rem = p % NN_;
  int u = rem / N_;
  int v = rem % N_;
  int xu = x[b * N_ + u], xv = x[b * N_ + v];
  int pk = A[p];
  int lab = pk ? (pk & 7) : 5;
  W[gid] = nemb[xu * 64 + d] + nemb[xv * 64 + d] + eemb[lab * 64 + d];
}

// ---------------- prep: transpose weights to [e][d] bf16 ----------------
__global__ void k_prep(const float* __restrict__ W1, const float* __restrict__ W2,
                       const float* __restrict__ Wm, u16* __restrict__ WT)
{
  int idx = blockIdx.x * 256 + threadIdx.x;   // 15*4096
  if (idx >= 15 * 4096) return;
  int l3 = idx >> 12;
  int r  = idx & 4095;
  int e = r >> 6, d = r & 63;
  int l = l3 / 3, which = l3 % 3;
  const float* s = which == 0 ? W1 : which == 1 ? W2 : Wm;
  WT[idx] = (u16)f2bf(s[l * 4096 + d * 64 + e]);
}

// ---------------- per-layer norm coefficients ----------------
__global__ void k_ns(const float* __restrict__ st, const float* __restrict__ gm,
                     const float* __restrict__ bt, float* __restrict__ ns)
{
  int i = blockIdx.x * 256 + threadIdx.x;  // 2048
  if (i >= B_ * 64) return;
  int d = i & 63;
  float S1 = st[i * 2], S2 = st[i * 2 + 1];
  float mu = S1 * INV_NN;
  float var = fmaf(S2, INV_NN, -mu * mu);
  float rsig = rsqrtf(var + EPS_);
  float sc = gm[d] * rsig;
  ns[i * 2] = sc;
  ns[i * 2 + 1] = fmaf(-mu, sc, bt[d]);
}

// ---------------- k_lin: out[e][q] = relu(norm(W)@Wt + b) (opt mask, opt transposed pair order) ----------------
template<int MASK>
__launch_bounds__(256)
__global__ void k_lin(const float* __restrict__ W, const u16* __restrict__ WTl,
                      const float* __restrict__ bias, const int* __restrict__ A,
                      const float* __restrict__ ns, int use_norm,
                      u16* __restrict__ out)
{
  __shared__ u16 Cs[64 * 264];
  const int tid = threadIdx.x;
  const int wave = tid >> 6, lane = tid & 63;
  const int lm = lane & 15, lg = lane >> 4;
  const int b = blockIdx.x / 36;
  const int qbase = (blockIdx.x % 36) * 256;

  bf16x8 aF[4][2];
  #pragma unroll
  for (int et = 0; et < 4; ++et)
    #pragma unroll
    for (int s = 0; s < 2; ++s)
      aF[et][s] = *(const bf16x8*)(WTl + (et * 16 + lm) * 64 + s * 32 + lg * 8);

  float sc[2][8], sh[2][8];
  if (use_norm) {
    #pragma unroll
    for (int s = 0; s < 2; ++s)
      #pragma unroll
      for (int jj = 0; jj < 8; jj += 2) {
        float4 t = *(const float4*)(ns + ((size_t)b * 64 + s * 32 + lg * 8 + jj) * 2);
        sc[s][jj] = t.x; sh[s][jj] = t.y; sc[s][jj + 1] = t.z; sh[s][jj + 1] = t.w;
      }
  } else {
    #pragma unroll
    for (int s = 0; s < 2; ++s)
      #pragma unroll
      for (int j = 0; j < 8; ++j) { sc[s][j] = 1.f; sh[s][j] = 0.f; }
  }

  const f32x4 zf = {0.f, 0.f, 0.f, 0.f};
  f32x4 acc[4][4];
  #pragma unroll
  for (int i = 0; i < 4; ++i)
    #pragma unroll
    for (int j = 0; j < 4; ++j) acc[i][j] = zf;

  int flags[4];
  #pragma unroll
  for (int qt = 0; qt < 4; ++qt) {
    int q = qbase + wave * 64 + qt * 16 + lm;
    int p;
    if (MASK) { int v = q / 96; int w = q - v * 96; p = w * 96 + v; }
    else p = q;
    const float* wrow = W + ((size_t)b * NN_ + p) * 64;
    if (MASK) flags[qt] = (A[b * NN_ + p] != 0);
    bf16x8 bF[2];
    #pragma unroll
    for (int s = 0; s < 2; ++s) {
      float4 f0 = *(const float4*)(wrow + s * 32 + lg * 8);
      float4 f1 = *(const float4*)(wrow + s * 32 + lg * 8 + 4);
      float v8[8] = {f0.x, f0.y, f0.z, f0.w, f1.x, f1.y, f1.z, f1.w};
      bf16x8 bb;
      #pragma unroll
      for (int j = 0; j < 8; ++j) {
        float v = v8[j];
        if (use_norm) v = fmaxf(fmaf(v, sc[s][j], sh[s][j]), 0.f);
        bb[j] = (short)f2bf(v);
      }
      bF[s] = bb;
    }
    #pragma unroll
    for (int s = 0; s < 2; ++s)
      #pragma unroll
      for (int et = 0; et < 4; ++et)
        acc[qt][et] = __builtin_amdgcn_mfma_f32_16x16x32_bf16(aF[et][s], bF[s], acc[qt][et], 0, 0, 0);
  }

  #pragma unroll
  for (int et = 0; et < 4; ++et) {
    float4 bs = *(const float4*)(bias + et * 16 + lg * 4);
    float bv[4] = {bs.x, bs.y, bs.z, bs.w};
    #pragma unroll
    for (int qt = 0; qt < 4; ++qt) {
      int col = wave * 64 + qt * 16 + lm;
      #pragma unroll
      for (int r = 0; r < 4; ++r) {
        float v = fmaxf(acc[qt][et][r] + bv[r], 0.f);
        if (MASK && !flags[qt]) v = 0.f;
        Cs[(et * 16 + lg * 4 + r) * 264 + col] = (u16)f2bf(v);
      }
    }
  }
  __syncthreads();
  u16* ob = out + (size_t)b * 64 * NN_ + qbase;
  for (int i = tid; i < 2048; i += 256) {
    int e = i >> 5, qc = (i & 31) * 8;
    uint4 val = *(const uint4*)&Cs[e * 264 + qc];
    *(uint4*)(ob + (size_t)e * NN_ + qc) = val;
  }
}

// ---------------- einsum: per (b,d) 96x96x96, operands direct from global ----------------
__launch_bounds__(256)
__global__ void k_einsum(const u16* __restrict__ h1, const u16* __restrict__ g2t,
                         u16* __restrict__ M)
{
  __shared__ u16 Cs[96 * 104];
  const int tid = threadIdx.x;
  const int wave = tid >> 6, lane = tid & 63;
  const int lm = lane & 15, lg = lane >> 4;
  const int bd = blockIdx.x;
  const u16* h1p = h1 + (size_t)bd * NN_;
  const u16* g2p = g2t + (size_t)bd * NN_;
  const int u0 = (wave & 1) * 48, v0 = (wave >> 1) * 48;

  bf16x8 aF[3][3], bF[3][3];
  #pragma unroll
  for (int t = 0; t < 3; ++t)
    #pragma unroll
    for (int s = 0; s < 3; ++s) {
      aF[t][s] = *(const bf16x8*)(h1p + (u0 + t * 16 + lm) * 96 + s * 32 + lg * 8);
      bF[t][s] = *(const bf16x8*)(g2p + (v0 + t * 16 + lm) * 96 + s * 32 + lg * 8);
    }
  const f32x4 zf = {0.f, 0.f, 0.f, 0.f};
  f32x4 acc[3][3];
  #pragma unroll
  for (int i = 0; i < 3; ++i)
    #pragma unroll
    for (int j = 0; j < 3; ++j) acc[i][j] = zf;
  #pragma unroll
  for (int s = 0; s < 3; ++s)
    #pragma unroll
    for (int ut = 0; ut < 3; ++ut)
      #pragma unroll
      for (int vt = 0; vt < 3; ++vt)
        acc[ut][vt] = __builtin_amdgcn_mfma_f32_16x16x32_bf16(aF[ut][s], bF[vt][s], acc[ut][vt], 0, 0, 0);

  #pragma unroll
  for (int ut = 0; ut < 3; ++ut)
    #pragma unroll
    for (int vt = 0; vt < 3; ++vt)
      #pragma unroll
      for (int r = 0; r < 4; ++r)
        Cs[(u0 + ut * 16 + lg * 4 + r) * 104 + v0 + vt * 16 + lm] = (u16)f2bf(acc[ut][vt][r]);
  __syncthreads();
  u16* Mp = M + (size_t)bd * NN_;
  for (int i = tid; i < 1152; i += 256) {
    int u = i / 12, vc = (i % 12) * 8;
    uint4 val = *(const uint4*)&Cs[u * 104 + vc];
    *(uint4*)(Mp + u * 96 + vc) = val;
  }
}

// ---------------- update: W[q][e] = res + (M@Wm)[q][e] + bm; stats ----------------
__launch_bounds__(256)
__global__ void k_update(const u16* __restrict__ M, const u16* __restrict__ WmT,
                         const float* __restrict__ bml, float* __restrict__ W,
                         const float* __restrict__ ns, int use_norm,
                         float* __restrict__ sto)
{
  __shared__ u16 Mt[128 * 64];
  __shared__ float red[128];
  const int tid = threadIdx.x;
  const int wave = tid >> 6, lane = tid & 63;
  const int lm = lane & 15, lg = lane >> 4;
  const int b = blockIdx.x / 72;
  const int qblk = (blockIdx.x % 72) * 128;

  if (tid < 128) red[tid] = 0.f;

  {
    const int ql = (tid & 63) + ((tid >> 6) & 1) * 64;
    const int d0 = (tid >> 7) * 32;
    const size_t gbase = (size_t)(b * 64) * NN_ + qblk + ql;
    #pragma unroll
    for (int dd = 0; dd < 32; ++dd) {
      int d = d0 + dd;
      u16 m = M[gbase + (size_t)d * NN_];
      int swz = (d >> 3) ^ (ql & 7);
      Mt[ql * 64 + swz * 8 + (d & 7)] = m;
    }
  }
  __syncthreads();

  bf16x8 aF[4][2];
  #pragma unroll
  for (int et = 0; et < 4; ++et)
    #pragma unroll
    for (int s = 0; s < 2; ++s)
      aF[et][s] = *(const bf16x8*)(WmT + (et * 16 + lm) * 64 + s * 32 + lg * 8);

  const f32x4 zf = {0.f, 0.f, 0.f, 0.f};
  f32x4 acc[2][4];
  #pragma unroll
  for (int i = 0; i < 2; ++i)
    #pragma unroll
    for (int j = 0; j < 4; ++j) acc[i][j] = zf;

  #pragma unroll
  for (int qtL = 0; qtL < 2; ++qtL) {
    int ql = (wave * 2 + qtL) * 16 + lm;
    bf16x8 bF[2];
    #pragma unroll
    for (int s = 0; s < 2; ++s) {
      int slot = s * 4 + lg;
      bF[s] = *(const bf16x8*)&Mt[ql * 64 + ((slot ^ (ql & 7)) * 8)];
    }
    #pragma unroll
    for (int s = 0; s < 2; ++s)
      #pragma unroll
      for (int et = 0; et < 4; ++et)
        acc[qtL][et] = __builtin_amdgcn_mfma_f32_16x16x32_bf16(aF[et][s], bF[s], acc[qtL][et], 0, 0, 0);
  }

  float s1[4][4], s2[4][4];
  #pragma unroll
  for (int i = 0; i < 4; ++i)
    #pragma unroll
    for (int j = 0; j < 4; ++j) { s1[i][j] = 0.f; s2[i][j] = 0.f; }

  #pragma unroll
  for (int et = 0; et < 4; ++et) {
    float4 bs = *(const float4*)(bml + et * 16 + lg * 4);
    float bv[4] = {bs.x, bs.y, bs.z, bs.w};
    float scn[4], shn[4];
    if (use_norm) {
      float4 t0 = *(const float4*)(ns + ((size_t)b * 64 + et * 16 + lg * 4) * 2);
      float4 t1 = *(const float4*)(ns + ((size_t)b * 64 + et * 16 + lg * 4) * 2 + 4);
      scn[0] = t0.x; shn[0] = t0.y; scn[1] = t0.z; shn[1] = t0.w;
      scn[2] = t1.x; shn[2] = t1.y; scn[3] = t1.z; shn[3] = t1.w;
    } else {
      #pragma unroll
      for (int r = 0; r < 4; ++r) { scn[r] = 1.f; shn[r] = 0.f; }
    }
    #pragma unroll
    for (int qtL = 0; qtL < 2; ++qtL) {
      int qg = qblk + (wave * 2 + qtL) * 16 + lm;
      float* Wp = W + ((size_t)b * NN_ + qg) * 64 + et * 16 + lg * 4;
      float4 wo = *(const float4*)Wp;
      float wv[4] = {wo.x, wo.y, wo.z, wo.w};
      float o[4];
      #pragma unroll
      for (int r = 0; r < 4; ++r) {
        float res = use_norm ? fmaxf(fmaf(wv[r], scn[r], shn[r]), 0.f) : wv[r];
        float val = acc[qtL][et][r] + bv[r] + res;
        o[r] = val;
        s1[et][r] += val;
        s2[et][r] = fmaf(val, val, s2[et][r]);
      }
      float4 ov = {o[0], o[1], o[2], o[3]};
      *(float4*)Wp = ov;
    }
  }

  #pragma unroll
  for (int et = 0; et < 4; ++et)
    #pragma unroll
    for (int r = 0; r < 4; ++r) {
      float a = s1[et][r], c = s2[et][r];
      a += __shfl_xor(a, 1, 64); a += __shfl_xor(a, 2, 64);
      a += __shfl_xor(a, 4, 64); a += __shfl_xor(a, 8, 64);
      c += __shfl_xor(c, 1, 64); c += __shfl_xor(c, 2, 64);
      c += __shfl_xor(c, 4, 64); c += __shfl_xor(c, 8, 64);
      if (lm == 0) {
        int e = et * 16 + lg * 4 + r;
        atomicAdd(&red[e], a);
        atomicAdd(&red[64 + e], c);
      }
    }
  __syncthreads();
  if (tid < 64) atomicAdd(&sto[((size_t)b * 64 + tid) * 2], red[tid]);
  else if (tid < 128) atomicAdd(&sto[((size_t)b * 64 + (tid - 64)) * 2 + 1], red[tid]);
}

// ---------------- pooling ----------------
__launch_bounds__(256)
__global__ void k_pool(const float* __restrict__ W,
                       const float* __restrict__ st,
                       const float* __restrict__ gml, const float* __restrict__ btl,
                       const float* __restrict__ pw, const float* __restrict__ pb,
                       float* __restrict__ out)
{
  const int b = blockIdx.x / 24;
  const int chunk = blockIdx.x % 24;
  const int tid = threadIdx.x;
  const int e = tid & 63;
  float S1 = st[(b * 64 + e) * 2], S2 = st[(b * 64 + e) * 2 + 1];
  float mu = S1 * INV_NN;
  float var = fmaf(S2, INV_NN, -mu * mu);
  float rsig = rsqrtf(var + EPS_);
  float scl = gml[e] * rsig;
  float shf = fmaf(-mu, scl, btl[e]);
  float pwv = pw[e];
  const float* base = W + (size_t)b * NN_ * 64 + chunk * 24576;
  float s = 0.f;
  for (int k = 0; k < 96; k++) {
    float w = base[k * 256 + tid];
    s += fmaxf(fmaf(w, scl, shf), 0.f) * pwv;
  }
  for (int o = 32; o; o >>= 1) s += __shfl_down(s, o, 64);
  __shared__ float rs[4];
  if ((tid & 63) == 0) rs[tid >> 6] = s;
  __syncthreads();
  if (tid == 0) {
    float t = rs[0] + rs[1] + rs[2] + rs[3];
    if (chunk == 0) t += pb[0];
    atomicAdd(&out[b], t);
  }
}

extern "C" void kernel_launch(void* const* d_in, const int* in_sizes, int n_in,
                              void* d_out, int out_size, void* d_ws, size_t ws_size,
                              hipStream_t stream) {
  const int*   x    = (const int*)d_in[0];
  const int*   ei   = (const int*)d_in[1];
  const int*   ea   = (const int*)d_in[2];
  const float* nemb = (const float*)d_in[3];
  const float* eemb = (const float*)d_in[4];
  const float* W1   = (const float*)d_in[5];
  const float* b1   = (const float*)d_in[6];
  const float* W2   = (const float*)d_in[7];
  const float* b2   = (const float*)d_in[8];
  const float* Wm   = (const float*)d_in[9];
  const float* bm   = (const float*)d_in[10];
  const float* gm   = (const float*)d_in[11];
  const float* bt   = (const float*)d_in[12];
  const float* pw   = (const float*)d_in[13];
  const float* pb   = (const float*)d_in[14];

  char* ws = (char*)d_ws;
  const size_t OFF_A  = 0;                    // int[BNN]           1,179,648
  const size_t OFF_W  = 1179648;              // f32[BNN*64]       75,497,472
  const size_t OFF_H1 = 76677120;             // bf16[64B][NN]     37,748,736
  const size_t OFF_G2 = 114425856;            // bf16[64B][NN]     37,748,736
  const size_t OFF_M  = 152174592;            // bf16[64B][NN]     37,748,736
  const size_t OFF_ST = 189923328;            // f32[32][64][2]        16,384
  const size_t OFF_NS = 189939712;            // f32[32][64][2]        16,384
  const size_t OFF_WT = 189956096;            // bf16[15][64][64]     122,880
  const size_t NEED   = OFF_WT + 122880;
  if (ws_size < NEED) return;

  int*   A     = (int*)(ws + OFF_A);
  float* W     = (float*)(ws + OFF_W);
  u16*   h1    = (u16*)(ws + OFF_H1);
  u16*   g2t   = (u16*)(ws + OFF_G2);
  u16*   M     = (u16*)(ws + OFF_M);
  float* stats = (float*)(ws + OFF_ST);
  float* ns    = (float*)(ws + OFF_NS);
  u16*   WT    = (u16*)(ws + OFF_WT);
  float* out   = (float*)d_out;

  hipMemsetAsync(A, 0, 1179648, stream);
  hipMemsetAsync(stats, 0, 16384, stream);
  hipMemsetAsync(out, 0, 32 * sizeof(float), stream);

  k_prep<<<240, 256, 0, stream>>>(W1, W2, Wm, WT);
  k_scatter<<<96, 256, 0, stream>>>(ei, ea, A);
  k_winit<<<73728, 256, 0, stream>>>(x, A, nemb, eemb, W);

  for (int l = 0; l < L_; l++) {
    int un = (l > 0);
    if (un) {
      k_ns<<<8, 256, 0, stream>>>(stats, gm + (l - 1) * 64, bt + (l - 1) * 64, ns);
      hipMemsetAsync(stats, 0, 16384, stream);
    }
    k_lin<0><<<1152, 256, 0, stream>>>(W, WT + (l * 3 + 0) * 4096, b1 + l * 64, A, ns, un, h1);
    k_lin<1><<<1152, 256, 0, stream>>>(W, WT + (l * 3 + 1) * 4096, b2 + l * 64, A, ns, un, g2t);
    k_einsum<<<2048, 256, 0, stream>>>(h1, g2t, M);
    k_update<<<2304, 256, 0, stream>>>(M, WT + (l * 3 + 2) * 4096, bm + l * 64, W, ns, un, stats);
  }
  k_pool<<<768, 256, 0, stream>>>(W, stats, gm + 4 * 64, bt + 4 * 64, pw, pb, out);
}

// Round 4
// 624.048 us; speedup vs baseline: 1.6898x; 1.2422x over previous
//
#include <hip/hip_runtime.h>
#include <hip/hip_bf16.h>

#define B_ 32
#define N_ 96
#define D_ 64
#define L_ 5
#define BE_ 24576
#define NN_ 9216
#define BNN_ 294912
#define EPS_ 1e-5f
#define INV_NN (1.0f/9216.0f)

typedef unsigned short u16;
typedef unsigned int u32;
typedef __attribute__((ext_vector_type(8))) short bf16x8;
typedef __attribute__((ext_vector_type(4))) float f32x4;

__device__ __forceinline__ float bf2f(u16 r){ return __uint_as_float(((u32)r) << 16); }
__device__ __forceinline__ u32 f2bf(float f){
  u32 u = __float_as_uint(f);
  return (u + 0x7fffu + ((u >> 16) & 1u)) >> 16;   // RNE
}
__device__ __forceinline__ u32 pack2(float lo, float hi){
  return f2bf(lo) | (f2bf(hi) << 16);
}

// ---------------- scatter: build packed A (last-write-wins via priority) ----------------
__global__ void k_scatter(const int* __restrict__ ei, const int* __restrict__ ea,
                          int* __restrict__ A)
{
  int e = blockIdx.x * 256 + threadIdx.x;
  if (e >= BE_) return;
  int a = ei[e], bnode = ei[BE_ + e];
  int g = a / N_;
  int u = a % N_;
  int v = bnode % N_;
  int lab = ea[e] & 7;
  int base = g * NN_;
  atomicMax(&A[base + u * N_ + v], ((e + 1) << 3) | lab);
  atomicMax(&A[base + v * N_ + u], ((BE_ + e + 1) << 3) | lab);
}

// ---------------- W init (bf16, 2 channels/thread) ----------------
__launch_bounds__(256)
__global__ void k_winit(const int* __restrict__ x, const int* __restrict__ A,
                        const float* __restrict__ nemb, const float* __restrict__ eemb,
                        u16* __restrict__ W)
{
  int gid = blockIdx.x * 256 + threadIdx.x;      // over BNN_*32
  int d = (gid & 31) * 2;
  int p = gid >> 5;
  int b = p / NN_;
  int rem = p % NN_;
  int u = rem / N_;
  int v = rem % N_;
  int xu = x[b * N_ + u], xv = x[b * N_ + v];
  int pk = A[p];
  int lab = pk ? (pk & 7) : 5;
  float v0 = nemb[xu * 64 + d]     + nemb[xv * 64 + d]     + eemb[lab * 64 + d];
  float v1 = nemb[xu * 64 + d + 1] + nemb[xv * 64 + d + 1] + eemb[lab * 64 + d + 1];
  ((u32*)W)[gid] = pack2(v0, v1);
}

// ---------------- prep: transpose weights to [e][d] bf16 ----------------
__global__ void k_prep(const float* __restrict__ W1, const float* __restrict__ W2,
                       const float* __restrict__ Wm, u16* __restrict__ WT)
{
  int idx = blockIdx.x * 256 + threadIdx.x;   // 15*4096
  if (idx >= 15 * 4096) return;
  int l3 = idx >> 12;
  int r  = idx & 4095;
  int e = r >> 6, d = r & 63;
  int l = l3 / 3, which = l3 % 3;
  const float* s = which == 0 ? W1 : which == 1 ? W2 : Wm;
  WT[idx] = (u16)f2bf(s[l * 4096 + d * 64 + e]);
}

// ---------------- per-layer norm coefficients ----------------
__global__ void k_ns(const float* __restrict__ st, const float* __restrict__ gm,
                     const float* __restrict__ bt, float* __restrict__ ns)
{
  int i = blockIdx.x * 256 + threadIdx.x;  // 2048
  if (i >= B_ * 64) return;
  int d = i & 63;
  float S1 = st[i * 2], S2 = st[i * 2 + 1];
  float mu = S1 * INV_NN;
  float var = fmaf(S2, INV_NN, -mu * mu);
  float rsig = rsqrtf(var + EPS_);
  float sc = gm[d] * rsig;
  ns[i * 2] = sc;
  ns[i * 2 + 1] = fmaf(-mu, sc, bt[d]);
}

// ---------------- fused lin: h1 = relu(nW@W1+b1), g2 = relu(nW@W2+b2)*adj (both [e][q] natural) ----------------
__launch_bounds__(256)
__global__ void k_lin2(const u16* __restrict__ W, const u16* __restrict__ WT1,
                       const u16* __restrict__ WT2,
                       const float* __restrict__ b1l, const float* __restrict__ b2l,
                       const int* __restrict__ A, const float* __restrict__ ns,
                       int use_norm, u16* __restrict__ h1, u16* __restrict__ g2)
{
  __shared__ u16 Cs[64 * 264];
  const int tid = threadIdx.x;
  const int wave = tid >> 6, lane = tid & 63;
  const int lm = lane & 15, lg = lane >> 4;
  const int b = blockIdx.x / 36;
  const int qbase = (blockIdx.x % 36) * 256;

  float sc[2][8], sh[2][8];
  if (use_norm) {
    #pragma unroll
    for (int s = 0; s < 2; ++s)
      #pragma unroll
      for (int jj = 0; jj < 8; jj += 2) {
        float4 t = *(const float4*)(ns + ((size_t)b * 64 + s * 32 + lg * 8 + jj) * 2);
        sc[s][jj] = t.x; sh[s][jj] = t.y; sc[s][jj + 1] = t.z; sh[s][jj + 1] = t.w;
      }
  } else {
    #pragma unroll
    for (int s = 0; s < 2; ++s)
      #pragma unroll
      for (int j = 0; j < 8; ++j) { sc[s][j] = 1.f; sh[s][j] = 0.f; }
  }

  // B-fragments (normed W rows) + adjacency flags, natural pair order
  bf16x8 bF[4][2];
  int flags[4];
  #pragma unroll
  for (int qt = 0; qt < 4; ++qt) {
    int q = qbase + wave * 64 + qt * 16 + lm;
    const u16* wrow = W + ((size_t)b * NN_ + q) * 64;
    flags[qt] = A[b * NN_ + q];
    #pragma unroll
    for (int s = 0; s < 2; ++s) {
      bf16x8 raw = *(const bf16x8*)(wrow + s * 32 + lg * 8);
      if (use_norm) {
        bf16x8 bb;
        #pragma unroll
        for (int j = 0; j < 8; ++j) {
          float v = bf2f((u16)raw[j]);
          v = fmaxf(fmaf(v, sc[s][j], sh[s][j]), 0.f);
          bb[j] = (short)f2bf(v);
        }
        bF[qt][s] = bb;
      } else {
        bF[qt][s] = raw;
      }
    }
  }

  const f32x4 zf = {0.f, 0.f, 0.f, 0.f};

  // ---- pass 1: h1 ----
  {
    bf16x8 aF[4][2];
    #pragma unroll
    for (int et = 0; et < 4; ++et)
      #pragma unroll
      for (int s = 0; s < 2; ++s)
        aF[et][s] = *(const bf16x8*)(WT1 + (et * 16 + lm) * 64 + s * 32 + lg * 8);
    f32x4 acc[4][4];
    #pragma unroll
    for (int i = 0; i < 4; ++i)
      #pragma unroll
      for (int j = 0; j < 4; ++j) acc[i][j] = zf;
    #pragma unroll
    for (int qt = 0; qt < 4; ++qt)
      #pragma unroll
      for (int s = 0; s < 2; ++s)
        #pragma unroll
        for (int et = 0; et < 4; ++et)
          acc[qt][et] = __builtin_amdgcn_mfma_f32_16x16x32_bf16(aF[et][s], bF[qt][s], acc[qt][et], 0, 0, 0);
    #pragma unroll
    for (int et = 0; et < 4; ++et) {
      float4 bs = *(const float4*)(b1l + et * 16 + lg * 4);
      float bv[4] = {bs.x, bs.y, bs.z, bs.w};
      #pragma unroll
      for (int qt = 0; qt < 4; ++qt) {
        int col = wave * 64 + qt * 16 + lm;
        #pragma unroll
        for (int r = 0; r < 4; ++r)
          Cs[(et * 16 + lg * 4 + r) * 264 + col] = (u16)f2bf(fmaxf(acc[qt][et][r] + bv[r], 0.f));
      }
    }
  }
  __syncthreads();
  {
    u16* ob = h1 + (size_t)b * 64 * NN_ + qbase;
    for (int i = tid; i < 2048; i += 256) {
      int e = i >> 5, qc = (i & 31) * 8;
      uint4 val = *(const uint4*)&Cs[e * 264 + qc];
      *(uint4*)(ob + (size_t)e * NN_ + qc) = val;
    }
  }
  __syncthreads();

  // ---- pass 2: g2 (masked) ----
  {
    bf16x8 aF[4][2];
    #pragma unroll
    for (int et = 0; et < 4; ++et)
      #pragma unroll
      for (int s = 0; s < 2; ++s)
        aF[et][s] = *(const bf16x8*)(WT2 + (et * 16 + lm) * 64 + s * 32 + lg * 8);
    f32x4 acc[4][4];
    #pragma unroll
    for (int i = 0; i < 4; ++i)
      #pragma unroll
      for (int j = 0; j < 4; ++j) acc[i][j] = zf;
    #pragma unroll
    for (int qt = 0; qt < 4; ++qt)
      #pragma unroll
      for (int s = 0; s < 2; ++s)
        #pragma unroll
        for (int et = 0; et < 4; ++et)
          acc[qt][et] = __builtin_amdgcn_mfma_f32_16x16x32_bf16(aF[et][s], bF[qt][s], acc[qt][et], 0, 0, 0);
    #pragma unroll
    for (int et = 0; et < 4; ++et) {
      float4 bs = *(const float4*)(b2l + et * 16 + lg * 4);
      float bv[4] = {bs.x, bs.y, bs.z, bs.w};
      #pragma unroll
      for (int qt = 0; qt < 4; ++qt) {
        int col = wave * 64 + qt * 16 + lm;
        #pragma unroll
        for (int r = 0; r < 4; ++r) {
          float v = fmaxf(acc[qt][et][r] + bv[r], 0.f);
          if (!flags[qt]) v = 0.f;
          Cs[(et * 16 + lg * 4 + r) * 264 + col] = (u16)f2bf(v);
        }
      }
    }
  }
  __syncthreads();
  {
    u16* ob = g2 + (size_t)b * 64 * NN_ + qbase;
    for (int i = tid; i < 2048; i += 256) {
      int e = i >> 5, qc = (i & 31) * 8;
      uint4 val = *(const uint4*)&Cs[e * 264 + qc];
      *(uint4*)(ob + (size_t)e * NN_ + qc) = val;
    }
  }
}

// ---------------- einsum: per (b,d) 96x96x96; A direct, B via manual LDS transpose ----------------
__launch_bounds__(256)
__global__ void k_einsum(const u16* __restrict__ h1, const u16* __restrict__ g2n,
                         u16* __restrict__ M)
{
  // Bt: packed-pair transposed B: Bt[v][wp] = (g2[2wp][v], g2[2wp+1][v]),
  // row stride 60 u32 (48 used + pad). 96*60*4 = 23040 B. Reused as C-stage
  // (96x104 u16 = 19968 B).
  __shared__ u32 Bt[96 * 60];
  u16* Cst = (u16*)Bt;
  const int tid = threadIdx.x;
  const int wave = tid >> 6, lane = tid & 63;
  const int lm = lane & 15, lg = lane >> 4;
  const int bd = blockIdx.x;
  const u16* h1p = h1 + (size_t)bd * NN_;
  const u16* g2p = g2n + (size_t)bd * NN_;
  const int u0 = (wave & 1) * 48, v0 = (wave >> 1) * 48;

  // transpose-stage g2 into Bt
  #pragma unroll
  for (int it = 0; it < 9; ++it) {
    int p = it * 256 + tid;          // [0, 2304): wp = p/48, vh = 2*(p%48)
    int wp = p / 48, vh = (p % 48) * 2;
    u32 a = *(const u32*)(g2p + (2 * wp) * 96 + vh);       // g2[2wp][vh], g2[2wp][vh+1]
    u32 c = *(const u32*)(g2p + (2 * wp + 1) * 96 + vh);   // g2[2wp+1][vh], g2[2wp+1][vh+1]
    Bt[vh * 60 + wp]       = (a & 0xffffu) | (c << 16);
    Bt[(vh + 1) * 60 + wp] = (a >> 16) | (c & 0xffff0000u);
  }
  __syncthreads();

  // A fragments direct from global: lane lm = u-row, k = w = s*32 + lg*8 + j
  bf16x8 aF[3][3];
  #pragma unroll
  for (int t = 0; t < 3; ++t)
    #pragma unroll
    for (int s = 0; s < 3; ++s)
      aF[t][s] = *(const bf16x8*)(h1p + (u0 + t * 16 + lm) * 96 + s * 32 + lg * 8);

  // B fragments from Bt: lane lm = v-col, k = w = s*32 + lg*8 + j (contiguous b128)
  bf16x8 bF[3][3];
  #pragma unroll
  for (int vt = 0; vt < 3; ++vt)
    #pragma unroll
    for (int s = 0; s < 3; ++s)
      bF[vt][s] = *(const bf16x8*)&Bt[(v0 + vt * 16 + lm) * 60 + s * 16 + lg * 4];
  __syncthreads();   // all waves done reading Bt; reuse as C-stage

  const f32x4 zf = {0.f, 0.f, 0.f, 0.f};
  f32x4 acc[3][3];
  #pragma unroll
  for (int i = 0; i < 3; ++i)
    #pragma unroll
    for (int j = 0; j < 3; ++j) acc[i][j] = zf;
  #pragma unroll
  for (int s = 0; s < 3; ++s)
    #pragma unroll
    for (int ut = 0; ut < 3; ++ut)
      #pragma unroll
      for (int vt = 0; vt < 3; ++vt)
        acc[ut][vt] = __builtin_amdgcn_mfma_f32_16x16x32_bf16(aF[ut][s], bF[vt][s], acc[ut][vt], 0, 0, 0);

  #pragma unroll
  for (int ut = 0; ut < 3; ++ut)
    #pragma unroll
    for (int vt = 0; vt < 3; ++vt)
      #pragma unroll
      for (int r = 0; r < 4; ++r)
        Cst[(u0 + ut * 16 + lg * 4 + r) * 104 + v0 + vt * 16 + lm] = (u16)f2bf(acc[ut][vt][r]);
  __syncthreads();
  u16* Mp = M + (size_t)bd * NN_;
  for (int i = tid; i < 1152; i += 256) {
    int u = i / 12, vc = (i % 12) * 8;
    uint4 val = *(const uint4*)&Cst[u * 104 + vc];
    *(uint4*)(Mp + u * 96 + vc) = val;
  }
}

// ---------------- update: W[q][e] = res + (M@Wm)[q][e] + bm; stats (W bf16) ----------------
__launch_bounds__(256)
__global__ void k_update(const u16* __restrict__ M, const u16* __restrict__ WmT,
                         const float* __restrict__ bml, u16* __restrict__ W,
                         const float* __restrict__ ns, int use_norm,
                         float* __restrict__ sto)
{
  __shared__ u16 Mt[128 * 64];
  __shared__ float red[128];
  const int tid = threadIdx.x;
  const int wave = tid >> 6, lane = tid & 63;
  const int lm = lane & 15, lg = lane >> 4;
  const int b = blockIdx.x / 72;
  const int qblk = (blockIdx.x % 72) * 128;

  if (tid < 128) red[tid] = 0.f;

  {
    const int ql = (tid & 63) + ((tid >> 6) & 1) * 64;
    const int d0 = (tid >> 7) * 32;
    const size_t gbase = (size_t)(b * 64) * NN_ + qblk + ql;
    #pragma unroll
    for (int dd = 0; dd < 32; ++dd) {
      int d = d0 + dd;
      u16 m = M[gbase + (size_t)d * NN_];
      int swz = (d >> 3) ^ (ql & 7);
      Mt[ql * 64 + swz * 8 + (d & 7)] = m;
    }
  }
  __syncthreads();

  bf16x8 aF[4][2];
  #pragma unroll
  for (int et = 0; et < 4; ++et)
    #pragma unroll
    for (int s = 0; s < 2; ++s)
      aF[et][s] = *(const bf16x8*)(WmT + (et * 16 + lm) * 64 + s * 32 + lg * 8);

  const f32x4 zf = {0.f, 0.f, 0.f, 0.f};
  f32x4 acc[2][4];
  #pragma unroll
  for (int i = 0; i < 2; ++i)
    #pragma unroll
    for (int j = 0; j < 4; ++j) acc[i][j] = zf;

  #pragma unroll
  for (int qtL = 0; qtL < 2; ++qtL) {
    int ql = (wave * 2 + qtL) * 16 + lm;
    bf16x8 bF[2];
    #pragma unroll
    for (int s = 0; s < 2; ++s) {
      int slot = s * 4 + lg;
      bF[s] = *(const bf16x8*)&Mt[ql * 64 + ((slot ^ (ql & 7)) * 8)];
    }
    #pragma unroll
    for (int s = 0; s < 2; ++s)
      #pragma unroll
      for (int et = 0; et < 4; ++et)
        acc[qtL][et] = __builtin_amdgcn_mfma_f32_16x16x32_bf16(aF[et][s], bF[s], acc[qtL][et], 0, 0, 0);
  }

  float s1[4][4], s2[4][4];
  #pragma unroll
  for (int i = 0; i < 4; ++i)
    #pragma unroll
    for (int j = 0; j < 4; ++j) { s1[i][j] = 0.f; s2[i][j] = 0.f; }

  #pragma unroll
  for (int et = 0; et < 4; ++et) {
    float4 bs = *(const float4*)(bml + et * 16 + lg * 4);
    float bv[4] = {bs.x, bs.y, bs.z, bs.w};
    float scn[4], shn[4];
    if (use_norm) {
      float4 t0 = *(const float4*)(ns + ((size_t)b * 64 + et * 16 + lg * 4) * 2);
      float4 t1 = *(const float4*)(ns + ((size_t)b * 64 + et * 16 + lg * 4) * 2 + 4);
      scn[0] = t0.x; shn[0] = t0.y; scn[1] = t0.z; shn[1] = t0.w;
      scn[2] = t1.x; shn[2] = t1.y; scn[3] = t1.z; shn[3] = t1.w;
    } else {
      #pragma unroll
      for (int r = 0; r < 4; ++r) { scn[r] = 1.f; shn[r] = 0.f; }
    }
    #pragma unroll
    for (int qtL = 0; qtL < 2; ++qtL) {
      int qg = qblk + (wave * 2 + qtL) * 16 + lm;
      u16* Wp = W + ((size_t)b * NN_ + qg) * 64 + et * 16 + lg * 4;
      uint2 wo = *(const uint2*)Wp;
      float wv[4] = {bf2f((u16)(wo.x & 0xffff)), bf2f((u16)(wo.x >> 16)),
                     bf2f((u16)(wo.y & 0xffff)), bf2f((u16)(wo.y >> 16))};
      float o[4];
      #pragma unroll
      for (int r = 0; r < 4; ++r) {
        float res = use_norm ? fmaxf(fmaf(wv[r], scn[r], shn[r]), 0.f) : wv[r];
        float val = acc[qtL][et][r] + bv[r] + res;
        o[r] = val;
        s1[et][r] += val;
        s2[et][r] = fmaf(val, val, s2[et][r]);
      }
      uint2 ov;
      ov.x = pack2(o[0], o[1]);
      ov.y = pack2(o[2], o[3]);
      *(uint2*)Wp = ov;
    }
  }

  #pragma unroll
  for (int et = 0; et < 4; ++et)
    #pragma unroll
    for (int r = 0; r < 4; ++r) {
      float a = s1[et][r], c = s2[et][r];
      a += __shfl_xor(a, 1, 64); a += __shfl_xor(a, 2, 64);
      a += __shfl_xor(a, 4, 64); a += __shfl_xor(a, 8, 64);
      c += __shfl_xor(c, 1, 64); c += __shfl_xor(c, 2, 64);
      c += __shfl_xor(c, 4, 64); c += __shfl_xor(c, 8, 64);
      if (lm == 0) {
        int e = et * 16 + lg * 4 + r;
        atomicAdd(&red[e], a);
        atomicAdd(&red[64 + e], c);
      }
    }
  __syncthreads();
  if (tid < 64) atomicAdd(&sto[((size_t)b * 64 + tid) * 2], red[tid]);
  else if (tid < 128) atomicAdd(&sto[((size_t)b * 64 + (tid - 64)) * 2 + 1], red[tid]);
}

// ---------------- pooling (W bf16) ----------------
__launch_bounds__(256)
__global__ void k_pool(const u16* __restrict__ W,
                       const float* __restrict__ st,
                       const float* __restrict__ gml, const float* __restrict__ btl,
                       const float* __restrict__ pw, const float* __restrict__ pb,
                       float* __restrict__ out)
{
  const int b = blockIdx.x / 24;
  const int chunk = blockIdx.x % 24;
  const int tid = threadIdx.x;
  const int e = tid & 63;
  float S1 = st[(b * 64 + e) * 2], S2 = st[(b * 64 + e) * 2 + 1];
  float mu = S1 * INV_NN;
  float var = fmaf(S2, INV_NN, -mu * mu);
  float rsig = rsqrtf(var + EPS_);
  float scl = gml[e] * rsig;
  float shf = fmaf(-mu, scl, btl[e]);
  float pwv = pw[e];
  const u16* base = W + (size_t)b * NN_ * 64 + chunk * 24576;
  float s = 0.f;
  for (int k = 0; k < 96; k++) {
    float w = bf2f(base[k * 256 + tid]);
    s += fmaxf(fmaf(w, scl, shf), 0.f) * pwv;
  }
  for (int o = 32; o; o >>= 1) s += __shfl_down(s, o, 64);
  __shared__ float rs[4];
  if ((tid & 63) == 0) rs[tid >> 6] = s;
  __syncthreads();
  if (tid == 0) {
    float t = rs[0] + rs[1] + rs[2] + rs[3];
    if (chunk == 0) t += pb[0];
    atomicAdd(&out[b], t);
  }
}

extern "C" void kernel_launch(void* const* d_in, const int* in_sizes, int n_in,
                              void* d_out, int out_size, void* d_ws, size_t ws_size,
                              hipStream_t stream) {
  const int*   x    = (const int*)d_in[0];
  const int*   ei   = (const int*)d_in[1];
  const int*   ea   = (const int*)d_in[2];
  const float* nemb = (const float*)d_in[3];
  const float* eemb = (const float*)d_in[4];
  const float* W1   = (const float*)d_in[5];
  const float* b1   = (const float*)d_in[6];
  const float* W2   = (const float*)d_in[7];
  const float* b2   = (const float*)d_in[8];
  const float* Wm   = (const float*)d_in[9];
  const float* bm   = (const float*)d_in[10];
  const float* gm   = (const float*)d_in[11];
  const float* bt   = (const float*)d_in[12];
  const float* pw   = (const float*)d_in[13];
  const float* pb   = (const float*)d_in[14];

  char* ws = (char*)d_ws;
  const size_t OFF_A  = 0;                    // int[BNN]            1,179,648
  const size_t OFF_W  = 1179648;              // bf16[BNN*64]       37,748,736
  const size_t OFF_H1 = 38928384;             // bf16[64B][NN]      37,748,736
  const size_t OFF_G2 = 76677120;             // bf16[64B][NN]      37,748,736
  const size_t OFF_M  = 114425856;            // bf16[64B][NN]      37,748,736
  const size_t OFF_ST = 152174592;            // f32[32][64][2]         16,384
  const size_t OFF_NS = 152190976;            // f32[32][64][2]         16,384
  const size_t OFF_WT = 152207360;            // bf16[15][64][64]      122,880
  const size_t NEED   = OFF_WT + 122880;
  if (ws_size < NEED) return;

  int*   A     = (int*)(ws + OFF_A);
  u16*   W     = (u16*)(ws + OFF_W);
  u16*   h1    = (u16*)(ws + OFF_H1);
  u16*   g2n   = (u16*)(ws + OFF_G2);
  u16*   M     = (u16*)(ws + OFF_M);
  float* stats = (float*)(ws + OFF_ST);
  float* ns    = (float*)(ws + OFF_NS);
  u16*   WT    = (u16*)(ws + OFF_WT);
  float* out   = (float*)d_out;

  hipMemsetAsync(A, 0, 1179648, stream);
  hipMemsetAsync(stats, 0, 16384, stream);
  hipMemsetAsync(out, 0, 32 * sizeof(float), stream);

  k_prep<<<240, 256, 0, stream>>>(W1, W2, Wm, WT);
  k_scatter<<<96, 256, 0, stream>>>(ei, ea, A);
  k_winit<<<36864, 256, 0, stream>>>(x, A, nemb, eemb, W);

  for (int l = 0; l < L_; l++) {
    int un = (l > 0);
    if (un) {
      k_ns<<<8, 256, 0, stream>>>(stats, gm + (l - 1) * 64, bt + (l - 1) * 64, ns);
      hipMemsetAsync(stats, 0, 16384, stream);
    }
    k_lin2<<<1152, 256, 0, stream>>>(W, WT + (l * 3 + 0) * 4096, WT + (l * 3 + 1) * 4096,
                                     b1 + l * 64, b2 + l * 64, A, ns, un, h1, g2n);
    k_einsum<<<2048, 256, 0, stream>>>(h1, g2n, M);
    k_update<<<2304, 256, 0, stream>>>(M, WT + (l * 3 + 2) * 4096, bm + l * 64, W, ns, un, stats);
  }
  k_pool<<<768, 256, 0, stream>>>(W, stats, gm + 4 * 64, bt + 4 * 64, pw, pb, out);
}

// Round 5
// 615.260 us; speedup vs baseline: 1.7139x; 1.0143x over previous
//
#include <hip/hip_runtime.h>
#include <hip/hip_bf16.h>

#define B_ 32
#define N_ 96
#define D_ 64
#define L_ 5
#define BE_ 24576
#define NN_ 9216
#define BNN_ 294912
#define EPS_ 1e-5f
#define INV_NN (1.0f/9216.0f)

typedef unsigned short u16;
typedef unsigned int u32;
typedef __attribute__((ext_vector_type(8))) short bf16x8;
typedef __attribute__((ext_vector_type(4))) float f32x4;

__device__ __forceinline__ float bf2f(u16 r){ return __uint_as_float(((u32)r) << 16); }
__device__ __forceinline__ u32 f2bf(float f){
  u32 u = __float_as_uint(f);
  return (u + 0x7fffu + ((u >> 16) & 1u)) >> 16;   // RNE
}
__device__ __forceinline__ u32 pack2(float lo, float hi){
  return f2bf(lo) | (f2bf(hi) << 16);
}

// ---------------- scatter: build packed A (last-write-wins via priority) ----------------
__global__ void k_scatter(const int* __restrict__ ei, const int* __restrict__ ea,
                          int* __restrict__ A)
{
  int e = blockIdx.x * 256 + threadIdx.x;
  if (e >= BE_) return;
  int a = ei[e], bnode = ei[BE_ + e];
  int g = a / N_;
  int u = a % N_;
  int v = bnode % N_;
  int lab = ea[e] & 7;
  int base = g * NN_;
  atomicMax(&A[base + u * N_ + v], ((e + 1) << 3) | lab);
  atomicMax(&A[base + v * N_ + u], ((BE_ + e + 1) << 3) | lab);
}

// ---------------- W init (bf16, 2 channels/thread) ----------------
__launch_bounds__(256)
__global__ void k_winit(const int* __restrict__ x, const int* __restrict__ A,
                        const float* __restrict__ nemb, const float* __restrict__ eemb,
                        u16* __restrict__ W)
{
  int gid = blockIdx.x * 256 + threadIdx.x;      // over BNN_*32
  int d = (gid & 31) * 2;
  int p = gid >> 5;
  int b = p / NN_;
  int rem = p % NN_;
  int u = rem / N_;
  int v = rem % N_;
  int xu = x[b * N_ + u], xv = x[b * N_ + v];
  int pk = A[p];
  int lab = pk ? (pk & 7) : 5;
  float v0 = nemb[xu * 64 + d]     + nemb[xv * 64 + d]     + eemb[lab * 64 + d];
  float v1 = nemb[xu * 64 + d + 1] + nemb[xv * 64 + d + 1] + eemb[lab * 64 + d + 1];
  ((u32*)W)[gid] = pack2(v0, v1);
}

// ---------------- prep: transpose weights to [e][d] bf16 ----------------
__global__ void k_prep(const float* __restrict__ W1, const float* __restrict__ W2,
                       const float* __restrict__ Wm, u16* __restrict__ WT)
{
  int idx = blockIdx.x * 256 + threadIdx.x;   // 15*4096
  if (idx >= 15 * 4096) return;
  int l3 = idx >> 12;
  int r  = idx & 4095;
  int e = r >> 6, d = r & 63;
  int l = l3 / 3, which = l3 % 3;
  const float* s = which == 0 ? W1 : which == 1 ? W2 : Wm;
  WT[idx] = (u16)f2bf(s[l * 4096 + d * 64 + e]);
}

// ---------------- fused lin: h1 = relu(nW@W1+b1), g2 = relu(nW@W2+b2)*adj ----------------
__launch_bounds__(256)
__global__ void k_lin2(const u16* __restrict__ W, const u16* __restrict__ WT1,
                       const u16* __restrict__ WT2,
                       const float* __restrict__ b1l, const float* __restrict__ b2l,
                       const int* __restrict__ A,
                       const float* __restrict__ stp, const float* __restrict__ gml,
                       const float* __restrict__ btl,
                       int use_norm, u16* __restrict__ h1, u16* __restrict__ g2)
{
  __shared__ u16 Cs[64 * 264];
  const int tid = threadIdx.x;
  const int wave = tid >> 6, lane = tid & 63;
  const int lm = lane & 15, lg = lane >> 4;
  const int b = blockIdx.x / 36;
  const int qbase = (blockIdx.x % 36) * 256;

  float sc[2][8], sh[2][8];
  if (use_norm) {
    #pragma unroll
    for (int s = 0; s < 2; ++s) {
      int d0 = s * 32 + lg * 8;
      #pragma unroll
      for (int j = 0; j < 8; j += 2) {
        float4 t = *(const float4*)(stp + ((size_t)b * 64 + d0 + j) * 2);
        float2 g = *(const float2*)(gml + d0 + j);
        float2 bb = *(const float2*)(btl + d0 + j);
        float mu0 = t.x * INV_NN;
        float var0 = fmaf(t.y, INV_NN, -mu0 * mu0);
        float s0 = g.x * rsqrtf(var0 + EPS_);
        sc[s][j] = s0;
        sh[s][j] = fmaf(-mu0, s0, bb.x);
        float mu1 = t.z * INV_NN;
        float var1 = fmaf(t.w, INV_NN, -mu1 * mu1);
        float s1v = g.y * rsqrtf(var1 + EPS_);
        sc[s][j + 1] = s1v;
        sh[s][j + 1] = fmaf(-mu1, s1v, bb.y);
      }
    }
  } else {
    #pragma unroll
    for (int s = 0; s < 2; ++s)
      #pragma unroll
      for (int j = 0; j < 8; ++j) { sc[s][j] = 1.f; sh[s][j] = 0.f; }
  }

  // B-fragments (normed W rows) + adjacency flags, natural pair order
  bf16x8 bF[4][2];
  int flags[4];
  #pragma unroll
  for (int qt = 0; qt < 4; ++qt) {
    int q = qbase + wave * 64 + qt * 16 + lm;
    const u16* wrow = W + ((size_t)b * NN_ + q) * 64;
    flags[qt] = A[b * NN_ + q];
    #pragma unroll
    for (int s = 0; s < 2; ++s) {
      bf16x8 raw = *(const bf16x8*)(wrow + s * 32 + lg * 8);
      if (use_norm) {
        bf16x8 bb;
        #pragma unroll
        for (int j = 0; j < 8; ++j) {
          float v = bf2f((u16)raw[j]);
          v = fmaxf(fmaf(v, sc[s][j], sh[s][j]), 0.f);
          bb[j] = (short)f2bf(v);
        }
        bF[qt][s] = bb;
      } else {
        bF[qt][s] = raw;
      }
    }
  }

  const f32x4 zf = {0.f, 0.f, 0.f, 0.f};

  // ---- pass 1: h1 ----
  {
    bf16x8 aF[4][2];
    #pragma unroll
    for (int et = 0; et < 4; ++et)
      #pragma unroll
      for (int s = 0; s < 2; ++s)
        aF[et][s] = *(const bf16x8*)(WT1 + (et * 16 + lm) * 64 + s * 32 + lg * 8);
    f32x4 acc[4][4];
    #pragma unroll
    for (int i = 0; i < 4; ++i)
      #pragma unroll
      for (int j = 0; j < 4; ++j) acc[i][j] = zf;
    #pragma unroll
    for (int qt = 0; qt < 4; ++qt)
      #pragma unroll
      for (int s = 0; s < 2; ++s)
        #pragma unroll
        for (int et = 0; et < 4; ++et)
          acc[qt][et] = __builtin_amdgcn_mfma_f32_16x16x32_bf16(aF[et][s], bF[qt][s], acc[qt][et], 0, 0, 0);
    #pragma unroll
    for (int et = 0; et < 4; ++et) {
      float4 bs = *(const float4*)(b1l + et * 16 + lg * 4);
      float bv[4] = {bs.x, bs.y, bs.z, bs.w};
      #pragma unroll
      for (int qt = 0; qt < 4; ++qt) {
        int col = wave * 64 + qt * 16 + lm;
        #pragma unroll
        for (int r = 0; r < 4; ++r)
          Cs[(et * 16 + lg * 4 + r) * 264 + col] = (u16)f2bf(fmaxf(acc[qt][et][r] + bv[r], 0.f));
      }
    }
  }
  __syncthreads();
  {
    u16* ob = h1 + (size_t)b * 64 * NN_ + qbase;
    for (int i = tid; i < 2048; i += 256) {
      int e = i >> 5, qc = (i & 31) * 8;
      uint4 val = *(const uint4*)&Cs[e * 264 + qc];
      *(uint4*)(ob + (size_t)e * NN_ + qc) = val;
    }
  }
  __syncthreads();

  // ---- pass 2: g2 (masked) ----
  {
    bf16x8 aF[4][2];
    #pragma unroll
    for (int et = 0; et < 4; ++et)
      #pragma unroll
      for (int s = 0; s < 2; ++s)
        aF[et][s] = *(const bf16x8*)(WT2 + (et * 16 + lm) * 64 + s * 32 + lg * 8);
    f32x4 acc[4][4];
    #pragma unroll
    for (int i = 0; i < 4; ++i)
      #pragma unroll
      for (int j = 0; j < 4; ++j) acc[i][j] = zf;
    #pragma unroll
    for (int qt = 0; qt < 4; ++qt)
      #pragma unroll
      for (int s = 0; s < 2; ++s)
        #pragma unroll
        for (int et = 0; et < 4; ++et)
          acc[qt][et] = __builtin_amdgcn_mfma_f32_16x16x32_bf16(aF[et][s], bF[qt][s], acc[qt][et], 0, 0, 0);
    #pragma unroll
    for (int et = 0; et < 4; ++et) {
      float4 bs = *(const float4*)(b2l + et * 16 + lg * 4);
      float bv[4] = {bs.x, bs.y, bs.z, bs.w};
      #pragma unroll
      for (int qt = 0; qt < 4; ++qt) {
        int col = wave * 64 + qt * 16 + lm;
        #pragma unroll
        for (int r = 0; r < 4; ++r) {
          float v = fmaxf(acc[qt][et][r] + bv[r], 0.f);
          if (!flags[qt]) v = 0.f;
          Cs[(et * 16 + lg * 4 + r) * 264 + col] = (u16)f2bf(v);
        }
      }
    }
  }
  __syncthreads();
  {
    u16* ob = g2 + (size_t)b * 64 * NN_ + qbase;
    for (int i = tid; i < 2048; i += 256) {
      int e = i >> 5, qc = (i & 31) * 8;
      uint4 val = *(const uint4*)&Cs[e * 264 + qc];
      *(uint4*)(ob + (size_t)e * NN_ + qc) = val;
    }
  }
}

// ---------------- einsum: per (b,d) 96x96x96; A direct, B via manual LDS transpose ----------------
__launch_bounds__(256)
__global__ void k_einsum(const u16* __restrict__ h1, const u16* __restrict__ g2n,
                         u16* __restrict__ M)
{
  __shared__ u32 Bt[96 * 60];
  u16* Cst = (u16*)Bt;
  const int tid = threadIdx.x;
  const int wave = tid >> 6, lane = tid & 63;
  const int lm = lane & 15, lg = lane >> 4;
  const int bd = blockIdx.x;
  const u16* h1p = h1 + (size_t)bd * NN_;
  const u16* g2p = g2n + (size_t)bd * NN_;
  const int u0 = (wave & 1) * 48, v0 = (wave >> 1) * 48;

  // transpose-stage g2 into Bt
  #pragma unroll
  for (int it = 0; it < 9; ++it) {
    int p = it * 256 + tid;          // [0, 2304): wp = p/48, vh = 2*(p%48)
    int wp = p / 48, vh = (p % 48) * 2;
    u32 a = *(const u32*)(g2p + (2 * wp) * 96 + vh);
    u32 c = *(const u32*)(g2p + (2 * wp + 1) * 96 + vh);
    Bt[vh * 60 + wp]       = (a & 0xffffu) | (c << 16);
    Bt[(vh + 1) * 60 + wp] = (a >> 16) | (c & 0xffff0000u);
  }

  // A fragments direct from global (issued before barrier -> overlap)
  bf16x8 aF[3][3];
  #pragma unroll
  for (int t = 0; t < 3; ++t)
    #pragma unroll
    for (int s = 0; s < 3; ++s)
      aF[t][s] = *(const bf16x8*)(h1p + (u0 + t * 16 + lm) * 96 + s * 32 + lg * 8);
  __syncthreads();

  // B fragments from Bt: lane lm = v-col, k = w = s*32 + lg*8 + j (contiguous b128)
  bf16x8 bF[3][3];
  #pragma unroll
  for (int vt = 0; vt < 3; ++vt)
    #pragma unroll
    for (int s = 0; s < 3; ++s)
      bF[vt][s] = *(const bf16x8*)&Bt[(v0 + vt * 16 + lm) * 60 + s * 16 + lg * 4];
  __syncthreads();   // all waves done reading Bt; reuse as C-stage

  const f32x4 zf = {0.f, 0.f, 0.f, 0.f};
  f32x4 acc[3][3];
  #pragma unroll
  for (int i = 0; i < 3; ++i)
    #pragma unroll
    for (int j = 0; j < 3; ++j) acc[i][j] = zf;
  #pragma unroll
  for (int s = 0; s < 3; ++s)
    #pragma unroll
    for (int ut = 0; ut < 3; ++ut)
      #pragma unroll
      for (int vt = 0; vt < 3; ++vt)
        acc[ut][vt] = __builtin_amdgcn_mfma_f32_16x16x32_bf16(aF[ut][s], bF[vt][s], acc[ut][vt], 0, 0, 0);

  #pragma unroll
  for (int ut = 0; ut < 3; ++ut)
    #pragma unroll
    for (int vt = 0; vt < 3; ++vt)
      #pragma unroll
      for (int r = 0; r < 4; ++r)
        Cst[(u0 + ut * 16 + lg * 4 + r) * 104 + v0 + vt * 16 + lm] = (u16)f2bf(acc[ut][vt][r]);
  __syncthreads();
  u16* Mp = M + (size_t)bd * NN_;
  for (int i = tid; i < 1152; i += 256) {
    int u = i / 12, vc = (i % 12) * 8;
    uint4 val = *(const uint4*)&Cst[u * 104 + vc];
    *(uint4*)(Mp + u * 96 + vc) = val;
  }
}

// ---------------- update: W[q][e] = res + (M@Wm)[q][e] + bm; stats (W bf16) ----------------
__launch_bounds__(256)
__global__ void k_update(const u16* __restrict__ M, const u16* __restrict__ WmT,
                         const float* __restrict__ bml, u16* __restrict__ W,
                         const float* __restrict__ stp, const float* __restrict__ gml,
                         const float* __restrict__ btl, int use_norm,
                         float* __restrict__ sto)
{
  __shared__ u16 Mt[128 * 64];
  __shared__ float red[128];
  const int tid = threadIdx.x;
  const int wave = tid >> 6, lane = tid & 63;
  const int lm = lane & 15, lg = lane >> 4;
  const int b = blockIdx.x / 72;
  const int qblk = (blockIdx.x % 72) * 128;

  if (tid < 128) red[tid] = 0.f;

  // Wm fragments issued early (global, independent of LDS staging)
  bf16x8 aF[4][2];
  #pragma unroll
  for (int et = 0; et < 4; ++et)
    #pragma unroll
    for (int s = 0; s < 2; ++s)
      aF[et][s] = *(const bf16x8*)(WmT + (et * 16 + lm) * 64 + s * 32 + lg * 8);

  // staging: vectorized M loads (uint4 = 8 q along one d-plane), swizzled LDS scatter
  {
    const int dpl = tid >> 2;              // plane 0..63
    const int qob = tid & 3;
    const u16* Mb = M + (size_t)(b * 64 + dpl) * NN_ + qblk;
    #pragma unroll
    for (int t = 0; t < 4; ++t) {
      int qo = qob + t * 4;                // octet 0..15 (q = qo*8 .. +7)
      uint4 v = *(const uint4*)(Mb + qo * 8);
      u32 ws[4] = {v.x, v.y, v.z, v.w};
      #pragma unroll
      for (int h = 0; h < 4; ++h) {
        int j0 = h * 2;
        int q0 = qo * 8 + j0;
        int slot0 = (dpl >> 3) ^ j0 ^ (qo & 7);
        int slot1 = (dpl >> 3) ^ (j0 + 1) ^ (qo & 7);
        Mt[q0 * 64 + slot0 * 8 + (dpl & 7)]       = (u16)(ws[h] & 0xffffu);
        Mt[(q0 + 1) * 64 + slot1 * 8 + (dpl & 7)] = (u16)(ws[h] >> 16);
      }
    }
  }
  __syncthreads();

  const f32x4 zf = {0.f, 0.f, 0.f, 0.f};
  f32x4 acc[2][4];
  #pragma unroll
  for (int i = 0; i < 2; ++i)
    #pragma unroll
    for (int j = 0; j < 4; ++j) acc[i][j] = zf;

  #pragma unroll
  for (int qtL = 0; qtL < 2; ++qtL) {
    int ql = (wave * 2 + qtL) * 16 + lm;
    bf16x8 bF[2];
    #pragma unroll
    for (int s = 0; s < 2; ++s) {
      int slot = (s * 4 + lg) ^ (ql & 7) ^ ((ql >> 3) & 7);
      bF[s] = *(const bf16x8*)&Mt[ql * 64 + slot * 8];
    }
    #pragma unroll
    for (int s = 0; s < 2; ++s)
      #pragma unroll
      for (int et = 0; et < 4; ++et)
        acc[qtL][et] = __builtin_amdgcn_mfma_f32_16x16x32_bf16(aF[et][s], bF[s], acc[qtL][et], 0, 0, 0);
  }

  float s1[4][4], s2[4][4];
  #pragma unroll
  for (int i = 0; i < 4; ++i)
    #pragma unroll
    for (int j = 0; j < 4; ++j) { s1[i][j] = 0.f; s2[i][j] = 0.f; }

  #pragma unroll
  for (int et = 0; et < 4; ++et) {
    int e0 = et * 16 + lg * 4;
    float4 bs = *(const float4*)(bml + e0);
    float bv[4] = {bs.x, bs.y, bs.z, bs.w};
    float scn[4], shn[4];
    if (use_norm) {
      float4 t0 = *(const float4*)(stp + ((size_t)b * 64 + e0) * 2);
      float4 t1 = *(const float4*)(stp + ((size_t)b * 64 + e0) * 2 + 4);
      float4 gv = *(const float4*)(gml + e0);
      float4 bv2 = *(const float4*)(btl + e0);
      float S1v[4] = {t0.x, t0.z, t1.x, t1.z};
      float S2v[4] = {t0.y, t0.w, t1.y, t1.w};
      float gvv[4] = {gv.x, gv.y, gv.z, gv.w};
      float btv[4] = {bv2.x, bv2.y, bv2.z, bv2.w};
      #pragma unroll
      for (int r = 0; r < 4; ++r) {
        float mu = S1v[r] * INV_NN;
        float var = fmaf(S2v[r], INV_NN, -mu * mu);
        float s0 = gvv[r] * rsqrtf(var + EPS_);
        scn[r] = s0;
        shn[r] = fmaf(-mu, s0, btv[r]);
      }
    } else {
      #pragma unroll
      for (int r = 0; r < 4; ++r) { scn[r] = 1.f; shn[r] = 0.f; }
    }
    #pragma unroll
    for (int qtL = 0; qtL < 2; ++qtL) {
      int qg = qblk + (wave * 2 + qtL) * 16 + lm;
      u16* Wp = W + ((size_t)b * NN_ + qg) * 64 + e0;
      uint2 wo = *(const uint2*)Wp;
      float wv[4] = {bf2f((u16)(wo.x & 0xffff)), bf2f((u16)(wo.x >> 16)),
                     bf2f((u16)(wo.y & 0xffff)), bf2f((u16)(wo.y >> 16))};
      float o[4];
      #pragma unroll
      for (int r = 0; r < 4; ++r) {
        float res = use_norm ? fmaxf(fmaf(wv[r], scn[r], shn[r]), 0.f) : wv[r];
        float val = acc[qtL][et][r] + bv[r] + res;
        o[r] = val;
        s1[et][r] += val;
        s2[et][r] = fmaf(val, val, s2[et][r]);
      }
      uint2 ov;
      ov.x = pack2(o[0], o[1]);
      ov.y = pack2(o[2], o[3]);
      *(uint2*)Wp = ov;
    }
  }

  #pragma unroll
  for (int et = 0; et < 4; ++et)
    #pragma unroll
    for (int r = 0; r < 4; ++r) {
      float a = s1[et][r], c = s2[et][r];
      a += __shfl_xor(a, 1, 64); a += __shfl_xor(a, 2, 64);
      a += __shfl_xor(a, 4, 64); a += __shfl_xor(a, 8, 64);
      c += __shfl_xor(c, 1, 64); c += __shfl_xor(c, 2, 64);
      c += __shfl_xor(c, 4, 64); c += __shfl_xor(c, 8, 64);
      if (lm == 0) {
        int e = et * 16 + lg * 4 + r;
        atomicAdd(&red[e], a);
        atomicAdd(&red[64 + e], c);
      }
    }
  __syncthreads();
  if (tid < 64) atomicAdd(&sto[((size_t)b * 64 + tid) * 2], red[tid]);
  else if (tid < 128) atomicAdd(&sto[((size_t)b * 64 + (tid - 64)) * 2 + 1], red[tid]);
}

// ---------------- pooling (W bf16) ----------------
__launch_bounds__(256)
__global__ void k_pool(const u16* __restrict__ W,
                       const float* __restrict__ st,
                       const float* __restrict__ gml, const float* __restrict__ btl,
                       const float* __restrict__ pw, const float* __restrict__ pb,
                       float* __restrict__ out)
{
  const int b = blockIdx.x / 24;
  const int chunk = blockIdx.x % 24;
  const int tid = threadIdx.x;
  const int e = tid & 63;
  float S1 = st[(b * 64 + e) * 2], S2 = st[(b * 64 + e) * 2 + 1];
  float mu = S1 * INV_NN;
  float var = fmaf(S2, INV_NN, -mu * mu);
  float rsig = rsqrtf(var + EPS_);
  float scl = gml[e] * rsig;
  float shf = fmaf(-mu, scl, btl[e]);
  float pwv = pw[e];
  const u16* base = W + (size_t)b * NN_ * 64 + chunk * 24576;
  float s = 0.f;
  for (int k = 0; k < 96; k++) {
    float w = bf2f(base[k * 256 + tid]);
    s += fmaxf(fmaf(w, scl, shf), 0.f) * pwv;
  }
  for (int o = 32; o; o >>= 1) s += __shfl_down(s, o, 64);
  __shared__ float rs[4];
  if ((tid & 63) == 0) rs[tid >> 6] = s;
  __syncthreads();
  if (tid == 0) {
    float t = rs[0] + rs[1] + rs[2] + rs[3];
    if (chunk == 0) t += pb[0];
    atomicAdd(&out[b], t);
  }
}

extern "C" void kernel_launch(void* const* d_in, const int* in_sizes, int n_in,
                              void* d_out, int out_size, void* d_ws, size_t ws_size,
                              hipStream_t stream) {
  const int*   x    = (const int*)d_in[0];
  const int*   ei   = (const int*)d_in[1];
  const int*   ea   = (const int*)d_in[2];
  const float* nemb = (const float*)d_in[3];
  const float* eemb = (const float*)d_in[4];
  const float* W1   = (const float*)d_in[5];
  const float* b1   = (const float*)d_in[6];
  const float* W2   = (const float*)d_in[7];
  const float* b2   = (const float*)d_in[8];
  const float* Wm   = (const float*)d_in[9];
  const float* bm   = (const float*)d_in[10];
  const float* gm   = (const float*)d_in[11];
  const float* bt   = (const float*)d_in[12];
  const float* pw   = (const float*)d_in[13];
  const float* pb   = (const float*)d_in[14];

  char* ws = (char*)d_ws;
  const size_t OFF_A  = 0;                    // int[BNN]            1,179,648
  const size_t OFF_W  = 1179648;              // bf16[BNN*64]       37,748,736
  const size_t OFF_H1 = 38928384;             // bf16[64B][NN]      37,748,736
  const size_t OFF_G2 = 76677120;             // bf16[64B][NN]      37,748,736
  const size_t OFF_M  = 114425856;            // bf16[64B][NN]      37,748,736
  const size_t OFF_ST = 152174592;            // f32[5][32][64][2]      81,920
  const size_t OFF_WT = 152256512;            // bf16[15][64][64]      122,880
  const size_t NEED   = OFF_WT + 122880;
  if (ws_size < NEED) return;

  int*   A     = (int*)(ws + OFF_A);
  u16*   W     = (u16*)(ws + OFF_W);
  u16*   h1    = (u16*)(ws + OFF_H1);
  u16*   g2n   = (u16*)(ws + OFF_G2);
  u16*   M     = (u16*)(ws + OFF_M);
  float* stats = (float*)(ws + OFF_ST);
  u16*   WT    = (u16*)(ws + OFF_WT);
  float* out   = (float*)d_out;

  hipMemsetAsync(A, 0, 1179648, stream);
  hipMemsetAsync(stats, 0, 81920, stream);
  hipMemsetAsync(out, 0, 32 * sizeof(float), stream);

  k_prep<<<240, 256, 0, stream>>>(W1, W2, Wm, WT);
  k_scatter<<<96, 256, 0, stream>>>(ei, ea, A);
  k_winit<<<36864, 256, 0, stream>>>(x, A, nemb, eemb, W);

  for (int l = 0; l < L_; l++) {
    int un = (l > 0);
    const float* stp = un ? stats + (size_t)(l - 1) * 4096 : stats;
    const float* gml = un ? gm + (l - 1) * 64 : gm;
    const float* btl = un ? bt + (l - 1) * 64 : bt;
    float* sto = stats + (size_t)l * 4096;
    k_lin2<<<1152, 256, 0, stream>>>(W, WT + (l * 3 + 0) * 4096, WT + (l * 3 + 1) * 4096,
                                     b1 + l * 64, b2 + l * 64, A, stp, gml, btl, un, h1, g2n);
    k_einsum<<<2048, 256, 0, stream>>>(h1, g2n, M);
    k_update<<<2304, 256, 0, stream>>>(M, WT + (l * 3 + 2) * 4096, bm + l * 64, W,
                                       stp, gml, btl, un, sto);
  }
  k_pool<<<768, 256, 0, stream>>>(W, stats + 4 * 4096, gm + 4 * 64, bt + 4 * 64,
                                  pw, pb, out);
}

// Round 7
// 581.209 us; speedup vs baseline: 1.8143x; 1.0586x over previous
//
#include <hip/hip_runtime.h>
#include <hip/hip_bf16.h>

#define B_ 32
#define N_ 96
#define D_ 64
#define L_ 5
#define BE_ 24576
#define NN_ 9216
#define BNN_ 294912
#define EPS_ 1e-5f
#define INV_NN (1.0f/9216.0f)

typedef unsigned short u16;
typedef unsigned int u32;
typedef __attribute__((ext_vector_type(8))) short bf16x8;
typedef __attribute__((ext_vector_type(4))) float f32x4;

__device__ __forceinline__ float bf2f(u16 r){ return __uint_as_float(((u32)r) << 16); }
__device__ __forceinline__ u32 f2bf(float f){
  u32 u = __float_as_uint(f);
  return (u + 0x7fffu + ((u >> 16) & 1u)) >> 16;   // RNE
}
__device__ __forceinline__ u32 pack2(float lo, float hi){
  return f2bf(lo) | (f2bf(hi) << 16);
}

// ---------------- scatter: build packed A (last-write-wins via priority) ----------------
__global__ void k_scatter(const int* __restrict__ ei, const int* __restrict__ ea,
                          int* __restrict__ A)
{
  int e = blockIdx.x * 256 + threadIdx.x;
  if (e >= BE_) return;
  int a = ei[e], bnode = ei[BE_ + e];
  int g = a / N_;
  int u = a % N_;
  int v = bnode % N_;
  int lab = ea[e] & 7;
  int base = g * NN_;
  atomicMax(&A[base + u * N_ + v], ((e + 1) << 3) | lab);
  atomicMax(&A[base + v * N_ + u], ((BE_ + e + 1) << 3) | lab);
}

// ---------------- W init (bf16, 4 channels/thread) ----------------
__launch_bounds__(256)
__global__ void k_winit(const int* __restrict__ x, const int* __restrict__ A,
                        const float* __restrict__ nemb, const float* __restrict__ eemb,
                        u16* __restrict__ W)
{
  int gid = blockIdx.x * 256 + threadIdx.x;      // over BNN_*16
  int d = (gid & 15) * 4;
  int p = gid >> 4;
  int b = p / NN_;
  int rem = p % NN_;
  int u = rem / N_;
  int v = rem % N_;
  int xu = x[b * N_ + u], xv = x[b * N_ + v];
  int pk = A[p];
  int lab = pk ? (pk & 7) : 5;
  float4 nu = *(const float4*)(nemb + xu * 64 + d);
  float4 nv = *(const float4*)(nemb + xv * 64 + d);
  float4 ee = *(const float4*)(eemb + lab * 64 + d);
  uint2 o;
  o.x = pack2(nu.x + nv.x + ee.x, nu.y + nv.y + ee.y);
  o.y = pack2(nu.z + nv.z + ee.z, nu.w + nv.w + ee.w);
  ((uint2*)W)[gid] = o;
}

// ---------------- prep: transpose weights to [e][d] bf16 ----------------
__global__ void k_prep(const float* __restrict__ W1, const float* __restrict__ W2,
                       const float* __restrict__ Wm, u16* __restrict__ WT)
{
  int idx = blockIdx.x * 256 + threadIdx.x;   // 15*4096
  if (idx >= 15 * 4096) return;
  int l3 = idx >> 12;
  int r  = idx & 4095;
  int e = r >> 6, d = r & 63;
  int l = l3 / 3, which = l3 % 3;
  const float* s = which == 0 ? W1 : which == 1 ? W2 : Wm;
  WT[idx] = (u16)f2bf(s[l * 4096 + d * 64 + e]);
}

// ---------------- fused lin: h1 = relu(nW@W1+b1), g2 = relu(nW@W2+b2)*adj ----------------
__launch_bounds__(256)
__global__ void k_lin2(const u16* __restrict__ W, const u16* __restrict__ WT1,
                       const u16* __restrict__ WT2,
                       const float* __restrict__ b1l, const float* __restrict__ b2l,
                       const int* __restrict__ A,
                       const float* __restrict__ pst, const float* __restrict__ gml,
                       const float* __restrict__ btl, float* __restrict__ nsF,
                       int use_norm, u16* __restrict__ h1, u16* __restrict__ g2)
{
  __shared__ u16 Cs[64 * 264];
  __shared__ float nsS[128];
  const int tid = threadIdx.x;
  const int wave = tid >> 6, lane = tid & 63;
  const int lm = lane & 15, lg = lane >> 4;
  const int b = blockIdx.x / 36;
  const int qbase = (blockIdx.x % 36) * 256;

  // ---- reduce stat partials (144 chunks) for this graph ----
  if (use_norm) {
    if (tid < 128) {
      const float* p = pst + ((size_t)b * 144) * 128 + tid;
      float a0 = 0.f, a1 = 0.f, a2 = 0.f, a3 = 0.f;
      for (int i = 0; i < 144; i += 4) {
        a0 += p[(size_t)i * 128];
        a1 += p[(size_t)(i + 1) * 128];
        a2 += p[(size_t)(i + 2) * 128];
        a3 += p[(size_t)(i + 3) * 128];
      }
      nsS[tid] = (a0 + a1) + (a2 + a3);
    }
    __syncthreads();
  }

  float sc[2][8], sh[2][8];
  if (use_norm) {
    #pragma unroll
    for (int s = 0; s < 2; ++s) {
      int d0 = s * 32 + lg * 8;
      #pragma unroll
      for (int j = 0; j < 8; ++j) {
        int d = d0 + j;
        float S1 = nsS[d], S2 = nsS[64 + d];
        float mu = S1 * INV_NN;
        float var = fmaf(S2, INV_NN, -mu * mu);
        float s0 = gml[d] * rsqrtf(var + EPS_);
        sc[s][j] = s0;
        sh[s][j] = fmaf(-mu, s0, btl[d]);
      }
    }
    // one block per graph publishes finalized coefficients for k_update / k_pool
    if ((blockIdx.x % 36) == 0 && tid < 64) {
      float S1 = nsS[tid], S2 = nsS[64 + tid];
      float mu = S1 * INV_NN;
      float var = fmaf(S2, INV_NN, -mu * mu);
      float s0 = gml[tid] * rsqrtf(var + EPS_);
      nsF[((size_t)b * 64 + tid) * 2]     = s0;
      nsF[((size_t)b * 64 + tid) * 2 + 1] = fmaf(-mu, s0, btl[tid]);
    }
  } else {
    #pragma unroll
    for (int s = 0; s < 2; ++s)
      #pragma unroll
      for (int j = 0; j < 8; ++j) { sc[s][j] = 1.f; sh[s][j] = 0.f; }
  }

  // B-fragments (normed W rows) + adjacency flags, natural pair order
  bf16x8 bF[4][2];
  int flags[4];
  #pragma unroll
  for (int qt = 0; qt < 4; ++qt) {
    int q = qbase + wave * 64 + qt * 16 + lm;
    const u16* wrow = W + ((size_t)b * NN_ + q) * 64;
    flags[qt] = A[b * NN_ + q];
    #pragma unroll
    for (int s = 0; s < 2; ++s) {
      bf16x8 raw = *(const bf16x8*)(wrow + s * 32 + lg * 8);
      if (use_norm) {
        bf16x8 bb;
        #pragma unroll
        for (int j = 0; j < 8; ++j) {
          float v = bf2f((u16)raw[j]);
          v = fmaxf(fmaf(v, sc[s][j], sh[s][j]), 0.f);
          bb[j] = (short)f2bf(v);
        }
        bF[qt][s] = bb;
      } else {
        bF[qt][s] = raw;
      }
    }
  }

  const f32x4 zf = {0.f, 0.f, 0.f, 0.f};

  // ---- pass 1: h1 ----
  {
    bf16x8 aF[4][2];
    #pragma unroll
    for (int et = 0; et < 4; ++et)
      #pragma unroll
      for (int s = 0; s < 2; ++s)
        aF[et][s] = *(const bf16x8*)(WT1 + (et * 16 + lm) * 64 + s * 32 + lg * 8);
    f32x4 acc[4][4];
    #pragma unroll
    for (int i = 0; i < 4; ++i)
      #pragma unroll
      for (int j = 0; j < 4; ++j) acc[i][j] = zf;
    #pragma unroll
    for (int qt = 0; qt < 4; ++qt)
      #pragma unroll
      for (int s = 0; s < 2; ++s)
        #pragma unroll
        for (int et = 0; et < 4; ++et)
          acc[qt][et] = __builtin_amdgcn_mfma_f32_16x16x32_bf16(aF[et][s], bF[qt][s], acc[qt][et], 0, 0, 0);
    #pragma unroll
    for (int et = 0; et < 4; ++et) {
      float4 bs = *(const float4*)(b1l + et * 16 + lg * 4);
      float bv[4] = {bs.x, bs.y, bs.z, bs.w};
      #pragma unroll
      for (int qt = 0; qt < 4; ++qt) {
        int col = wave * 64 + qt * 16 + lm;
        #pragma unroll
        for (int r = 0; r < 4; ++r)
          Cs[(et * 16 + lg * 4 + r) * 264 + col] = (u16)f2bf(fmaxf(acc[qt][et][r] + bv[r], 0.f));
      }
    }
  }
  __syncthreads();
  {
    u16* ob = h1 + (size_t)b * 64 * NN_ + qbase;
    for (int i = tid; i < 2048; i += 256) {
      int e = i >> 5, qc = (i & 31) * 8;
      uint4 val = *(const uint4*)&Cs[e * 264 + qc];
      *(uint4*)(ob + (size_t)e * NN_ + qc) = val;
    }
  }
  __syncthreads();

  // ---- pass 2: g2 (masked) ----
  {
    bf16x8 aF[4][2];
    #pragma unroll
    for (int et = 0; et < 4; ++et)
      #pragma unroll
      for (int s = 0; s < 2; ++s)
        aF[et][s] = *(const bf16x8*)(WT2 + (et * 16 + lm) * 64 + s * 32 + lg * 8);
    f32x4 acc[4][4];
    #pragma unroll
    for (int i = 0; i < 4; ++i)
      #pragma unroll
      for (int j = 0; j < 4; ++j) acc[i][j] = zf;
    #pragma unroll
    for (int qt = 0; qt < 4; ++qt)
      #pragma unroll
      for (int s = 0; s < 2; ++s)
        #pragma unroll
        for (int et = 0; et < 4; ++et)
          acc[qt][et] = __builtin_amdgcn_mfma_f32_16x16x32_bf16(aF[et][s], bF[qt][s], acc[qt][et], 0, 0, 0);
    #pragma unroll
    for (int et = 0; et < 4; ++et) {
      float4 bs = *(const float4*)(b2l + et * 16 + lg * 4);
      float bv[4] = {bs.x, bs.y, bs.z, bs.w};
      #pragma unroll
      for (int qt = 0; qt < 4; ++qt) {
        int col = wave * 64 + qt * 16 + lm;
        #pragma unroll
        for (int r = 0; r < 4; ++r) {
          float v = fmaxf(acc[qt][et][r] + bv[r], 0.f);
          if (!flags[qt]) v = 0.f;
          Cs[(et * 16 + lg * 4 + r) * 264 + col] = (u16)f2bf(v);
        }
      }
    }
  }
  __syncthreads();
  {
    u16* ob = g2 + (size_t)b * 64 * NN_ + qbase;
    for (int i = tid; i < 2048; i += 256) {
      int e = i >> 5, qc = (i & 31) * 8;
      uint4 val = *(const uint4*)&Cs[e * 264 + qc];
      *(uint4*)(ob + (size_t)e * NN_ + qc) = val;
    }
  }
}

// ---------------- einsum: per (b,d) 96x96x96; A direct, B via manual LDS transpose ----------------
__launch_bounds__(256)
__global__ void k_einsum(const u16* __restrict__ h1, const u16* __restrict__ g2n,
                         u16* __restrict__ M)
{
  __shared__ u32 Bt[96 * 60];
  u16* Cst = (u16*)Bt;
  const int tid = threadIdx.x;
  const int wave = tid >> 6, lane = tid & 63;
  const int lm = lane & 15, lg = lane >> 4;
  const int bd = blockIdx.x;
  const u16* h1p = h1 + (size_t)bd * NN_;
  const u16* g2p = g2n + (size_t)bd * NN_;
  const int u0 = (wave & 1) * 48, v0 = (wave >> 1) * 48;

  // transpose-stage g2 into Bt
  #pragma unroll
  for (int it = 0; it < 9; ++it) {
    int p = it * 256 + tid;          // [0, 2304): wp = p/48, vh = 2*(p%48)
    int wp = p / 48, vh = (p % 48) * 2;
    u32 a = *(const u32*)(g2p + (2 * wp) * 96 + vh);
    u32 c = *(const u32*)(g2p + (2 * wp + 1) * 96 + vh);
    Bt[vh * 60 + wp]       = (a & 0xffffu) | (c << 16);
    Bt[(vh + 1) * 60 + wp] = (a >> 16) | (c & 0xffff0000u);
  }

  // A fragments direct from global (issued before barrier -> overlap)
  bf16x8 aF[3][3];
  #pragma unroll
  for (int t = 0; t < 3; ++t)
    #pragma unroll
    for (int s = 0; s < 3; ++s)
      aF[t][s] = *(const bf16x8*)(h1p + (u0 + t * 16 + lm) * 96 + s * 32 + lg * 8);
  __syncthreads();

  // B fragments from Bt: lane lm = v-col, k = w = s*32 + lg*8 + j (contiguous b128)
  bf16x8 bF[3][3];
  #pragma unroll
  for (int vt = 0; vt < 3; ++vt)
    #pragma unroll
    for (int s = 0; s < 3; ++s)
      bF[vt][s] = *(const bf16x8*)&Bt[(v0 + vt * 16 + lm) * 60 + s * 16 + lg * 4];
  __syncthreads();   // all waves done reading Bt; reuse as C-stage

  const f32x4 zf = {0.f, 0.f, 0.f, 0.f};
  f32x4 acc[3][3];
  #pragma unroll
  for (int i = 0; i < 3; ++i)
    #pragma unroll
    for (int j = 0; j < 3; ++j) acc[i][j] = zf;
  #pragma unroll
  for (int s = 0; s < 3; ++s)
    #pragma unroll
    for (int ut = 0; ut < 3; ++ut)
      #pragma unroll
      for (int vt = 0; vt < 3; ++vt)
        acc[ut][vt] = __builtin_amdgcn_mfma_f32_16x16x32_bf16(aF[ut][s], bF[vt][s], acc[ut][vt], 0, 0, 0);

  #pragma unroll
  for (int ut = 0; ut < 3; ++ut)
    #pragma unroll
    for (int vt = 0; vt < 3; ++vt)
      #pragma unroll
      for (int r = 0; r < 4; ++r)
        Cst[(u0 + ut * 16 + lg * 4 + r) * 104 + v0 + vt * 16 + lm] = (u16)f2bf(acc[ut][vt][r]);
  __syncthreads();
  u16* Mp = M + (size_t)bd * NN_;
  for (int i = tid; i < 1152; i += 256) {
    int u = i / 12, vc = (i % 12) * 8;
    uint4 val = *(const uint4*)&Cst[u * 104 + vc];
    *(uint4*)(Mp + u * 96 + vc) = val;
  }
}

// ---------------- update: W[q][e] = res + (M@Wm)[q][e] + bm; stat partials (no atomics) ----------------
__launch_bounds__(128)
__global__ void k_update(const u16* __restrict__ M, const u16* __restrict__ WmT,
                         const float* __restrict__ bml, u16* __restrict__ W,
                         const float* __restrict__ nsF, int use_norm,
                         float* __restrict__ pst)
{
  __shared__ u16 Mt[64 * 64];
  __shared__ float red[2][128];
  const int tid = threadIdx.x;
  const int wave = tid >> 6, lane = tid & 63;
  const int lm = lane & 15, lg = lane >> 4;
  const int b = blockIdx.x / 144;
  const int qi = blockIdx.x % 144;
  const int qblk = qi * 64;

  // early: Wm fragments (independent of staging)
  bf16x8 aF[4][2];
  #pragma unroll
  for (int et = 0; et < 4; ++et)
    #pragma unroll
    for (int s = 0; s < 2; ++s)
      aF[et][s] = *(const bf16x8*)(WmT + (et * 16 + lm) * 64 + s * 32 + lg * 8);

  // early: W residual rows (prefetched before barrier)
  uint2 wres[2][4];
  #pragma unroll
  for (int qtL = 0; qtL < 2; ++qtL) {
    int qg = qblk + (wave * 2 + qtL) * 16 + lm;
    const u16* Wp = W + ((size_t)b * NN_ + qg) * 64;
    #pragma unroll
    for (int et = 0; et < 4; ++et)
      wres[qtL][et] = *(const uint2*)(Wp + et * 16 + lg * 4);
  }

  // early: finalized norm coefficients (published by k_lin2 this layer)
  float scn[4][4], shn[4][4];
  if (use_norm) {
    #pragma unroll
    for (int et = 0; et < 4; ++et) {
      int e0 = et * 16 + lg * 4;
      float4 t0 = *(const float4*)(nsF + ((size_t)b * 64 + e0) * 2);
      float4 t1 = *(const float4*)(nsF + ((size_t)b * 64 + e0) * 2 + 4);
      scn[et][0] = t0.x; shn[et][0] = t0.y; scn[et][1] = t0.z; shn[et][1] = t0.w;
      scn[et][2] = t1.x; shn[et][2] = t1.y; scn[et][3] = t1.z; shn[et][3] = t1.w;
    }
  } else {
    #pragma unroll
    for (int et = 0; et < 4; ++et)
      #pragma unroll
      for (int r = 0; r < 4; ++r) { scn[et][r] = 1.f; shn[et][r] = 0.f; }
  }

  // staging: vectorized M loads, swizzled LDS scatter
  {
    const int dpl = tid >> 1;              // plane 0..63
    const int qob = tid & 1;
    const u16* Mb = M + (size_t)(b * 64 + dpl) * NN_ + qblk;
    #pragma unroll
    for (int t = 0; t < 4; ++t) {
      int qo = qob + t * 2;                // octet 0..7 (q = qo*8 .. +7)
      uint4 v = *(const uint4*)(Mb + qo * 8);
      u32 ws[4] = {v.x, v.y, v.z, v.w};
      #pragma unroll
      for (int h = 0; h < 4; ++h) {
        int j0 = h * 2;
        int q0 = qo * 8 + j0;
        int slot0 = (dpl >> 3) ^ j0 ^ (qo & 7);
        int slot1 = (dpl >> 3) ^ (j0 + 1) ^ (qo & 7);
        Mt[q0 * 64 + slot0 * 8 + (dpl & 7)]       = (u16)(ws[h] & 0xffffu);
        Mt[(q0 + 1) * 64 + slot1 * 8 + (dpl & 7)] = (u16)(ws[h] >> 16);
      }
    }
  }
  __syncthreads();

  const f32x4 zf = {0.f, 0.f, 0.f, 0.f};
  f32x4 acc[2][4];
  #pragma unroll
  for (int i = 0; i < 2; ++i)
    #pragma unroll
    for (int j = 0; j < 4; ++j) acc[i][j] = zf;

  #pragma unroll
  for (int qtL = 0; qtL < 2; ++qtL) {
    int ql = (wave * 2 + qtL) * 16 + lm;
    bf16x8 bF[2];
    #pragma unroll
    for (int s = 0; s < 2; ++s) {
      int slot = (s * 4 + lg) ^ (ql & 7) ^ ((ql >> 3) & 7);
      bF[s] = *(const bf16x8*)&Mt[ql * 64 + slot * 8];
    }
    #pragma unroll
    for (int s = 0; s < 2; ++s)
      #pragma unroll
      for (int et = 0; et < 4; ++et)
        acc[qtL][et] = __builtin_amdgcn_mfma_f32_16x16x32_bf16(aF[et][s], bF[s], acc[qtL][et], 0, 0, 0);
  }

  float s1[4][4], s2[4][4];
  #pragma unroll
  for (int i = 0; i < 4; ++i)
    #pragma unroll
    for (int j = 0; j < 4; ++j) { s1[i][j] = 0.f; s2[i][j] = 0.f; }

  #pragma unroll
  for (int et = 0; et < 4; ++et) {
    int e0 = et * 16 + lg * 4;
    float4 bs = *(const float4*)(bml + e0);
    float bv[4] = {bs.x, bs.y, bs.z, bs.w};
    #pragma unroll
    for (int qtL = 0; qtL < 2; ++qtL) {
      int qg = qblk + (wave * 2 + qtL) * 16 + lm;
      u16* Wp = W + ((size_t)b * NN_ + qg) * 64 + e0;
      uint2 wo = wres[qtL][et];
      float wv[4] = {bf2f((u16)(wo.x & 0xffff)), bf2f((u16)(wo.x >> 16)),
                     bf2f((u16)(wo.y & 0xffff)), bf2f((u16)(wo.y >> 16))};
      float o[4];
      #pragma unroll
      for (int r = 0; r < 4; ++r) {
        float res = use_norm ? fmaxf(fmaf(wv[r], scn[et][r], shn[et][r]), 0.f) : wv[r];
        float val = acc[qtL][et][r] + bv[r] + res;
        o[r] = val;
        s1[et][r] += val;
        s2[et][r] = fmaf(val, val, s2[et][r]);
      }
      uint2 ov;
      ov.x = pack2(o[0], o[1]);
      ov.y = pack2(o[2], o[3]);
      *(uint2*)Wp = ov;
    }
  }

  // wave-local reduce over lm, then block partial write (no atomics)
  #pragma unroll
  for (int et = 0; et < 4; ++et)
    #pragma unroll
    for (int r = 0; r < 4; ++r) {
      float a = s1[et][r], c = s2[et][r];
      a += __shfl_xor(a, 1, 64); a += __shfl_xor(a, 2, 64);
      a += __shfl_xor(a, 4, 64); a += __shfl_xor(a, 8, 64);
      c += __shfl_xor(c, 1, 64); c += __shfl_xor(c, 2, 64);
      c += __shfl_xor(c, 4, 64); c += __shfl_xor(c, 8, 64);
      if (lm == 0) {
        int e = et * 16 + lg * 4 + r;
        red[wave][e]      = a;
        red[wave][64 + e] = c;
      }
    }
  __syncthreads();
  if (tid < 128)
    pst[((size_t)b * 144 + qi) * 128 + tid] = red[0][tid] + red[1][tid];
}

// ---------------- pooling (W bf16; reduces stat partials itself) ----------------
__launch_bounds__(256)
__global__ void k_pool(const u16* __restrict__ W,
                       const float* __restrict__ pst,
                       const float* __restrict__ gml, const float* __restrict__ btl,
                       const float* __restrict__ pw, const float* __restrict__ pb,
                       float* __restrict__ out)
{
  __shared__ float nsS[128];
  const int b = blockIdx.x / 24;
  const int chunk = blockIdx.x % 24;
  const int tid = threadIdx.x;
  if (tid < 128) {
    const float* p = pst + ((size_t)b * 144) * 128 + tid;
    float a0 = 0.f, a1 = 0.f, a2 = 0.f, a3 = 0.f;
    for (int i = 0; i < 144; i += 4) {
      a0 += p[(size_t)i * 128];
      a1 += p[(size_t)(i + 1) * 128];
      a2 += p[(size_t)(i + 2) * 128];
      a3 += p[(size_t)(i + 3) * 128];
    }
    nsS[tid] = (a0 + a1) + (a2 + a3);
  }
  __syncthreads();
  const int e = tid & 63;
  float S1 = nsS[e], S2 = nsS[64 + e];
  float mu = S1 * INV_NN;
  float var = fmaf(S2, INV_NN, -mu * mu);
  float rsig = rsqrtf(var + EPS_);
  float scl = gml[e] * rsig;
  float shf = fmaf(-mu, scl, btl[e]);
  float pwv = pw[e];
  const u16* base = W + (size_t)b * NN_ * 64 + chunk * 24576;
  float s = 0.f;
  for (int k = 0; k < 96; k++) {
    float w = bf2f(base[k * 256 + tid]);
    s += fmaxf(fmaf(w, scl, shf), 0.f) * pwv;
  }
  for (int o = 32; o; o >>= 1) s += __shfl_down(s, o, 64);
  __shared__ float rs[4];
  if ((tid & 63) == 0) rs[tid >> 6] = s;
  __syncthreads();
  if (tid == 0) {
    float t = rs[0] + rs[1] + rs[2] + rs[3];
    if (chunk == 0) t += pb[0];
    atomicAdd(&out[b], t);
  }
}

extern "C" void kernel_launch(void* const* d_in, const int* in_sizes, int n_in,
                              void* d_out, int out_size, void* d_ws, size_t ws_size,
                              hipStream_t stream) {
  const int*   x    = (const int*)d_in[0];
  const int*   ei   = (const int*)d_in[1];
  const int*   ea   = (const int*)d_in[2];
  const float* nemb = (const float*)d_in[3];
  const float* eemb = (const float*)d_in[4];
  const float* W1   = (const float*)d_in[5];
  const float* b1   = (const float*)d_in[6];
  const float* W2   = (const float*)d_in[7];
  const float* b2   = (const float*)d_in[8];
  const float* Wm   = (const float*)d_in[9];
  const float* bm   = (const float*)d_in[10];
  const float* gm   = (const float*)d_in[11];
  const float* bt   = (const float*)d_in[12];
  const float* pw   = (const float*)d_in[13];
  const float* pb   = (const float*)d_in[14];

  char* ws = (char*)d_ws;
  const size_t OFF_A  = 0;                    // int[BNN]            1,179,648
  const size_t OFF_W  = 1179648;              // bf16[BNN*64]       37,748,736
  const size_t OFF_H1 = 38928384;             // bf16[64B][NN]      37,748,736
  const size_t OFF_G2 = 76677120;             // bf16[64B][NN]      37,748,736
  const size_t OFF_M  = 114425856;            // bf16[64B][NN]      37,748,736
  const size_t OFF_PS = 152174592;            // f32[32][144][128]   2,359,296
  const size_t OFF_NF = 154533888;            // f32[32][64][2]         16,384
  const size_t OFF_WT = 154550272;            // bf16[15][64][64]      122,880
  const size_t NEED   = OFF_WT + 122880;
  if (ws_size < NEED) return;

  int*   A     = (int*)(ws + OFF_A);
  u16*   W     = (u16*)(ws + OFF_W);
  u16*   h1    = (u16*)(ws + OFF_H1);
  u16*   g2n   = (u16*)(ws + OFF_G2);
  u16*   M     = (u16*)(ws + OFF_M);
  float* pst   = (float*)(ws + OFF_PS);
  float* nsF   = (float*)(ws + OFF_NF);
  u16*   WT    = (u16*)(ws + OFF_WT);
  float* out   = (float*)d_out;

  hipMemsetAsync(A, 0, 1179648, stream);
  hipMemsetAsync(out, 0, 32 * sizeof(float), stream);

  k_prep<<<240, 256, 0, stream>>>(W1, W2, Wm, WT);
  k_scatter<<<96, 256, 0, stream>>>(ei, ea, A);
  k_winit<<<18432, 256, 0, stream>>>(x, A, nemb, eemb, W);

  for (int l = 0; l < L_; l++) {
    int un = (l > 0);
    const float* gml = un ? gm + (l - 1) * 64 : gm;
    const float* btl = un ? bt + (l - 1) * 64 : bt;
    k_lin2<<<1152, 256, 0, stream>>>(W, WT + (l * 3 + 0) * 4096, WT + (l * 3 + 1) * 4096,
                                     b1 + l * 64, b2 + l * 64, A, pst, gml, btl, nsF,
                                     un, h1, g2n);
    k_einsum<<<2048, 256, 0, stream>>>(h1, g2n, M);
    k_update<<<4608, 128, 0, stream>>>(M, WT + (l * 3 + 2) * 4096, bm + l * 64, W,
                                       nsF, un, pst);
  }
  k_pool<<<768, 256, 0, stream>>>(W, pst, gm + 4 * 64, bt + 4 * 64, pw, pb, out);
}

// Round 8
// 551.035 us; speedup vs baseline: 1.9137x; 1.0548x over previous
//
#include <hip/hip_runtime.h>
#include <hip/hip_bf16.h>

#define B_ 32
#define N_ 96
#define D_ 64
#define L_ 5
#define BE_ 24576
#define NN_ 9216
#define BNN_ 294912
#define EPS_ 1e-5f
#define INV_NN (1.0f/9216.0f)

typedef unsigned short u16;
typedef unsigned int u32;
typedef __attribute__((ext_vector_type(8))) short bf16x8;
typedef __attribute__((ext_vector_type(4))) float f32x4;

__device__ __forceinline__ float bf2f(u16 r){ return __uint_as_float(((u32)r) << 16); }
__device__ __forceinline__ u32 f2bf(float f){
  u32 u = __float_as_uint(f);
  return (u + 0x7fffu + ((u >> 16) & 1u)) >> 16;   // RNE
}
__device__ __forceinline__ u32 pack2(float lo, float hi){
  return f2bf(lo) | (f2bf(hi) << 16);
}

// ---------------- scatter: build packed A (last-write-wins via priority) ----------------
__global__ void k_scatter(const int* __restrict__ ei, const int* __restrict__ ea,
                          int* __restrict__ A)
{
  int e = blockIdx.x * 256 + threadIdx.x;
  if (e >= BE_) return;
  int a = ei[e], bnode = ei[BE_ + e];
  int g = a / N_;
  int u = a % N_;
  int v = bnode % N_;
  int lab = ea[e] & 7;
  int base = g * NN_;
  atomicMax(&A[base + u * N_ + v], ((e + 1) << 3) | lab);
  atomicMax(&A[base + v * N_ + u], ((BE_ + e + 1) << 3) | lab);
}

// ---------------- W init (bf16, 4 channels/thread) ----------------
__launch_bounds__(256)
__global__ void k_winit(const int* __restrict__ x, const int* __restrict__ A,
                        const float* __restrict__ nemb, const float* __restrict__ eemb,
                        u16* __restrict__ W)
{
  int gid = blockIdx.x * 256 + threadIdx.x;      // over BNN_*16
  int d = (gid & 15) * 4;
  int p = gid >> 4;
  int b = p / NN_;
  int rem = p % NN_;
  int u = rem / N_;
  int v = rem % N_;
  int xu = x[b * N_ + u], xv = x[b * N_ + v];
  int pk = A[p];
  int lab = pk ? (pk & 7) : 5;
  float4 nu = *(const float4*)(nemb + xu * 64 + d);
  float4 nv = *(const float4*)(nemb + xv * 64 + d);
  float4 ee = *(const float4*)(eemb + lab * 64 + d);
  uint2 o;
  o.x = pack2(nu.x + nv.x + ee.x, nu.y + nv.y + ee.y);
  o.y = pack2(nu.z + nv.z + ee.z, nu.w + nv.w + ee.w);
  ((uint2*)W)[gid] = o;
}

// ---------------- prep: transpose weights to [e][d] bf16 ----------------
__global__ void k_prep(const float* __restrict__ W1, const float* __restrict__ W2,
                       const float* __restrict__ Wm, u16* __restrict__ WT)
{
  int idx = blockIdx.x * 256 + threadIdx.x;   // 15*4096
  if (idx >= 15 * 4096) return;
  int l3 = idx >> 12;
  int r  = idx & 4095;
  int e = r >> 6, d = r & 63;
  int l = l3 / 3, which = l3 % 3;
  const float* s = which == 0 ? W1 : which == 1 ? W2 : Wm;
  WT[idx] = (u16)f2bf(s[l * 4096 + d * 64 + e]);
}

// ---------------- fused lin: h1 = relu(nW@W1+b1), g2 = relu(nW@W2+b2)*adj ----------------
__launch_bounds__(256, 4)
__global__ void k_lin2(const u16* __restrict__ W, const u16* __restrict__ WT1,
                       const u16* __restrict__ WT2,
                       const float* __restrict__ b1l, const float* __restrict__ b2l,
                       const int* __restrict__ A,
                       const float* __restrict__ pst, const float* __restrict__ gml,
                       const float* __restrict__ btl, float* __restrict__ nsF,
                       int use_norm, u16* __restrict__ h1, u16* __restrict__ g2)
{
  __shared__ u16 Cs[64 * 264];
  __shared__ float nsS[128];
  const int tid = threadIdx.x;
  const int wave = tid >> 6, lane = tid & 63;
  const int lm = lane & 15, lg = lane >> 4;
  const int b = blockIdx.x / 36;
  const int qbase = (blockIdx.x % 36) * 256;

  // ---- reduce stat partials (144 chunks) for this graph ----
  if (use_norm) {
    if (tid < 128) {
      const float* p = pst + ((size_t)b * 144) * 128 + tid;
      float a0 = 0.f, a1 = 0.f, a2 = 0.f, a3 = 0.f;
      for (int i = 0; i < 144; i += 4) {
        a0 += p[(size_t)i * 128];
        a1 += p[(size_t)(i + 1) * 128];
        a2 += p[(size_t)(i + 2) * 128];
        a3 += p[(size_t)(i + 3) * 128];
      }
      nsS[tid] = (a0 + a1) + (a2 + a3);
    }
    __syncthreads();
  }

  float sc[2][8], sh[2][8];
  if (use_norm) {
    #pragma unroll
    for (int s = 0; s < 2; ++s) {
      int d0 = s * 32 + lg * 8;
      #pragma unroll
      for (int j = 0; j < 8; ++j) {
        int d = d0 + j;
        float S1 = nsS[d], S2 = nsS[64 + d];
        float mu = S1 * INV_NN;
        float var = fmaf(S2, INV_NN, -mu * mu);
        float s0 = gml[d] * rsqrtf(var + EPS_);
        sc[s][j] = s0;
        sh[s][j] = fmaf(-mu, s0, btl[d]);
      }
    }
    // one block per graph publishes finalized coefficients for k_update / k_pool
    if ((blockIdx.x % 36) == 0 && tid < 64) {
      float S1 = nsS[tid], S2 = nsS[64 + tid];
      float mu = S1 * INV_NN;
      float var = fmaf(S2, INV_NN, -mu * mu);
      float s0 = gml[tid] * rsqrtf(var + EPS_);
      nsF[((size_t)b * 64 + tid) * 2]     = s0;
      nsF[((size_t)b * 64 + tid) * 2 + 1] = fmaf(-mu, s0, btl[tid]);
    }
  } else {
    #pragma unroll
    for (int s = 0; s < 2; ++s)
      #pragma unroll
      for (int j = 0; j < 8; ++j) { sc[s][j] = 1.f; sh[s][j] = 0.f; }
  }

  // B-fragments (normed W rows) + adjacency flags, natural pair order
  bf16x8 bF[4][2];
  int flags[4];
  #pragma unroll
  for (int qt = 0; qt < 4; ++qt) {
    int q = qbase + wave * 64 + qt * 16 + lm;
    const u16* wrow = W + ((size_t)b * NN_ + q) * 64;
    flags[qt] = A[b * NN_ + q];
    #pragma unroll
    for (int s = 0; s < 2; ++s) {
      bf16x8 raw = *(const bf16x8*)(wrow + s * 32 + lg * 8);
      if (use_norm) {
        bf16x8 bb;
        #pragma unroll
        for (int j = 0; j < 8; ++j) {
          float v = bf2f((u16)raw[j]);
          v = fmaxf(fmaf(v, sc[s][j], sh[s][j]), 0.f);
          bb[j] = (short)f2bf(v);
        }
        bF[qt][s] = bb;
      } else {
        bF[qt][s] = raw;
      }
    }
  }

  const f32x4 zf = {0.f, 0.f, 0.f, 0.f};

  // ---- pass 1: h1 (qt-outer: only 4 accumulators live) ----
  {
    bf16x8 aF[4][2];
    #pragma unroll
    for (int et = 0; et < 4; ++et)
      #pragma unroll
      for (int s = 0; s < 2; ++s)
        aF[et][s] = *(const bf16x8*)(WT1 + (et * 16 + lm) * 64 + s * 32 + lg * 8);
    float4 bsv[4];
    #pragma unroll
    for (int et = 0; et < 4; ++et) bsv[et] = *(const float4*)(b1l + et * 16 + lg * 4);
    #pragma unroll
    for (int qt = 0; qt < 4; ++qt) {
      f32x4 acc[4] = {zf, zf, zf, zf};
      #pragma unroll
      for (int s = 0; s < 2; ++s)
        #pragma unroll
        for (int et = 0; et < 4; ++et)
          acc[et] = __builtin_amdgcn_mfma_f32_16x16x32_bf16(aF[et][s], bF[qt][s], acc[et], 0, 0, 0);
      int col = wave * 64 + qt * 16 + lm;
      #pragma unroll
      for (int et = 0; et < 4; ++et) {
        float bv[4] = {bsv[et].x, bsv[et].y, bsv[et].z, bsv[et].w};
        #pragma unroll
        for (int r = 0; r < 4; ++r)
          Cs[(et * 16 + lg * 4 + r) * 264 + col] = (u16)f2bf(fmaxf(acc[et][r] + bv[r], 0.f));
      }
    }
  }
  __syncthreads();
  {
    u16* ob = h1 + (size_t)b * 64 * NN_ + qbase;
    for (int i = tid; i < 2048; i += 256) {
      int e = i >> 5, qc = (i & 31) * 8;
      uint4 val = *(const uint4*)&Cs[e * 264 + qc];
      *(uint4*)(ob + (size_t)e * NN_ + qc) = val;
    }
  }
  __syncthreads();

  // ---- pass 2: g2 (masked), qt-outer ----
  {
    bf16x8 aF[4][2];
    #pragma unroll
    for (int et = 0; et < 4; ++et)
      #pragma unroll
      for (int s = 0; s < 2; ++s)
        aF[et][s] = *(const bf16x8*)(WT2 + (et * 16 + lm) * 64 + s * 32 + lg * 8);
    float4 bsv[4];
    #pragma unroll
    for (int et = 0; et < 4; ++et) bsv[et] = *(const float4*)(b2l + et * 16 + lg * 4);
    #pragma unroll
    for (int qt = 0; qt < 4; ++qt) {
      f32x4 acc[4] = {zf, zf, zf, zf};
      #pragma unroll
      for (int s = 0; s < 2; ++s)
        #pragma unroll
        for (int et = 0; et < 4; ++et)
          acc[et] = __builtin_amdgcn_mfma_f32_16x16x32_bf16(aF[et][s], bF[qt][s], acc[et], 0, 0, 0);
      int col = wave * 64 + qt * 16 + lm;
      #pragma unroll
      for (int et = 0; et < 4; ++et) {
        float bv[4] = {bsv[et].x, bsv[et].y, bsv[et].z, bsv[et].w};
        #pragma unroll
        for (int r = 0; r < 4; ++r) {
          float v = fmaxf(acc[et][r] + bv[r], 0.f);
          if (!flags[qt]) v = 0.f;
          Cs[(et * 16 + lg * 4 + r) * 264 + col] = (u16)f2bf(v);
        }
      }
    }
  }
  __syncthreads();
  {
    u16* ob = g2 + (size_t)b * 64 * NN_ + qbase;
    for (int i = tid; i < 2048; i += 256) {
      int e = i >> 5, qc = (i & 31) * 8;
      uint4 val = *(const uint4*)&Cs[e * 264 + qc];
      *(uint4*)(ob + (size_t)e * NN_ + qc) = val;
    }
  }
}

// ---------------- einsum: per (b,d) 96x96x96; A direct, B via manual LDS transpose ----------------
__launch_bounds__(256, 4)
__global__ void k_einsum(const u16* __restrict__ h1, const u16* __restrict__ g2n,
                         u16* __restrict__ M)
{
  __shared__ u32 Bt[96 * 60];
  u16* Cst = (u16*)Bt;
  const int tid = threadIdx.x;
  const int wave = tid >> 6, lane = tid & 63;
  const int lm = lane & 15, lg = lane >> 4;
  const int bd = blockIdx.x;
  const u16* h1p = h1 + (size_t)bd * NN_;
  const u16* g2p = g2n + (size_t)bd * NN_;
  const int u0 = (wave & 1) * 48, v0 = (wave >> 1) * 48;

  // transpose-stage g2 into Bt
  #pragma unroll
  for (int it = 0; it < 9; ++it) {
    int p = it * 256 + tid;          // [0, 2304): wp = p/48, vh = 2*(p%48)
    int wp = p / 48, vh = (p % 48) * 2;
    u32 a = *(const u32*)(g2p + (2 * wp) * 96 + vh);
    u32 c = *(const u32*)(g2p + (2 * wp + 1) * 96 + vh);
    Bt[vh * 60 + wp]       = (a & 0xffffu) | (c << 16);
    Bt[(vh + 1) * 60 + wp] = (a >> 16) | (c & 0xffff0000u);
  }

  // A fragments direct from global (issued before barrier -> overlap)
  bf16x8 aF[3][3];
  #pragma unroll
  for (int t = 0; t < 3; ++t)
    #pragma unroll
    for (int s = 0; s < 3; ++s)
      aF[t][s] = *(const bf16x8*)(h1p + (u0 + t * 16 + lm) * 96 + s * 32 + lg * 8);
  __syncthreads();

  const f32x4 zf = {0.f, 0.f, 0.f, 0.f};
  f32x4 acc[3][3];
  #pragma unroll
  for (int i = 0; i < 3; ++i)
    #pragma unroll
    for (int j = 0; j < 3; ++j) acc[i][j] = zf;

  // per-s B fragments (only 3 live at a time)
  #pragma unroll
  for (int s = 0; s < 3; ++s) {
    bf16x8 bb[3];
    #pragma unroll
    for (int vt = 0; vt < 3; ++vt)
      bb[vt] = *(const bf16x8*)&Bt[(v0 + vt * 16 + lm) * 60 + s * 16 + lg * 4];
    #pragma unroll
    for (int ut = 0; ut < 3; ++ut)
      #pragma unroll
      for (int vt = 0; vt < 3; ++vt)
        acc[ut][vt] = __builtin_amdgcn_mfma_f32_16x16x32_bf16(aF[ut][s], bb[vt], acc[ut][vt], 0, 0, 0);
  }
  __syncthreads();   // all waves done reading Bt; reuse as C-stage

  #pragma unroll
  for (int ut = 0; ut < 3; ++ut)
    #pragma unroll
    for (int vt = 0; vt < 3; ++vt)
      #pragma unroll
      for (int r = 0; r < 4; ++r)
        Cst[(u0 + ut * 16 + lg * 4 + r) * 104 + v0 + vt * 16 + lm] = (u16)f2bf(acc[ut][vt][r]);
  __syncthreads();
  u16* Mp = M + (size_t)bd * NN_;
  for (int i = tid; i < 1152; i += 256) {
    int u = i / 12, vc = (i % 12) * 8;
    uint4 val = *(const uint4*)&Cst[u * 104 + vc];
    *(uint4*)(Mp + u * 96 + vc) = val;
  }
}

// ---------------- update: W[q][e] = res + (M@Wm)[q][e] + bm; stat partials (no atomics) ----------------
__launch_bounds__(128)
__global__ void k_update(const u16* __restrict__ M, const u16* __restrict__ WmT,
                         const float* __restrict__ bml, u16* __restrict__ W,
                         const float* __restrict__ nsF, int use_norm,
                         float* __restrict__ pst)
{
  __shared__ u16 Mt[64 * 64];
  __shared__ float red[2][128];
  const int tid = threadIdx.x;
  const int wave = tid >> 6, lane = tid & 63;
  const int lm = lane & 15, lg = lane >> 4;
  const int b = blockIdx.x / 144;
  const int qi = blockIdx.x % 144;
  const int qblk = qi * 64;

  // early: Wm fragments (independent of staging)
  bf16x8 aF[4][2];
  #pragma unroll
  for (int et = 0; et < 4; ++et)
    #pragma unroll
    for (int s = 0; s < 2; ++s)
      aF[et][s] = *(const bf16x8*)(WmT + (et * 16 + lm) * 64 + s * 32 + lg * 8);

  // early: W residual rows (prefetched before barrier)
  uint2 wres[2][4];
  #pragma unroll
  for (int qtL = 0; qtL < 2; ++qtL) {
    int qg = qblk + (wave * 2 + qtL) * 16 + lm;
    const u16* Wp = W + ((size_t)b * NN_ + qg) * 64;
    #pragma unroll
    for (int et = 0; et < 4; ++et)
      wres[qtL][et] = *(const uint2*)(Wp + et * 16 + lg * 4);
  }

  // early: finalized norm coefficients (published by k_lin2 this layer)
  float scn[4][4], shn[4][4];
  if (use_norm) {
    #pragma unroll
    for (int et = 0; et < 4; ++et) {
      int e0 = et * 16 + lg * 4;
      float4 t0 = *(const float4*)(nsF + ((size_t)b * 64 + e0) * 2);
      float4 t1 = *(const float4*)(nsF + ((size_t)b * 64 + e0) * 2 + 4);
      scn[et][0] = t0.x; shn[et][0] = t0.y; scn[et][1] = t0.z; shn[et][1] = t0.w;
      scn[et][2] = t1.x; shn[et][2] = t1.y; scn[et][3] = t1.z; shn[et][3] = t1.w;
    }
  } else {
    #pragma unroll
    for (int et = 0; et < 4; ++et)
      #pragma unroll
      for (int r = 0; r < 4; ++r) { scn[et][r] = 1.f; shn[et][r] = 0.f; }
  }

  // staging: vectorized M loads, swizzled LDS scatter
  {
    const int dpl = tid >> 1;              // plane 0..63
    const int qob = tid & 1;
    const u16* Mb = M + (size_t)(b * 64 + dpl) * NN_ + qblk;
    #pragma unroll
    for (int t = 0; t < 4; ++t) {
      int qo = qob + t * 2;                // octet 0..7 (q = qo*8 .. +7)
      uint4 v = *(const uint4*)(Mb + qo * 8);
      u32 ws[4] = {v.x, v.y, v.z, v.w};
      #pragma unroll
      for (int h = 0; h < 4; ++h) {
        int j0 = h * 2;
        int q0 = qo * 8 + j0;
        int slot0 = (dpl >> 3) ^ j0 ^ (qo & 7);
        int slot1 = (dpl >> 3) ^ (j0 + 1) ^ (qo & 7);
        Mt[q0 * 64 + slot0 * 8 + (dpl & 7)]       = (u16)(ws[h] & 0xffffu);
        Mt[(q0 + 1) * 64 + slot1 * 8 + (dpl & 7)] = (u16)(ws[h] >> 16);
      }
    }
  }
  __syncthreads();

  const f32x4 zf = {0.f, 0.f, 0.f, 0.f};
  f32x4 acc[2][4];
  #pragma unroll
  for (int i = 0; i < 2; ++i)
    #pragma unroll
    for (int j = 0; j < 4; ++j) acc[i][j] = zf;

  #pragma unroll
  for (int qtL = 0; qtL < 2; ++qtL) {
    int ql = (wave * 2 + qtL) * 16 + lm;
    bf16x8 bF[2];
    #pragma unroll
    for (int s = 0; s < 2; ++s) {
      int slot = (s * 4 + lg) ^ (ql & 7) ^ ((ql >> 3) & 7);
      bF[s] = *(const bf16x8*)&Mt[ql * 64 + slot * 8];
    }
    #pragma unroll
    for (int s = 0; s < 2; ++s)
      #pragma unroll
      for (int et = 0; et < 4; ++et)
        acc[qtL][et] = __builtin_amdgcn_mfma_f32_16x16x32_bf16(aF[et][s], bF[s], acc[qtL][et], 0, 0, 0);
  }

  float s1[4][4], s2[4][4];
  #pragma unroll
  for (int i = 0; i < 4; ++i)
    #pragma unroll
    for (int j = 0; j < 4; ++j) { s1[i][j] = 0.f; s2[i][j] = 0.f; }

  #pragma unroll
  for (int et = 0; et < 4; ++et) {
    int e0 = et * 16 + lg * 4;
    float4 bs = *(const float4*)(bml + e0);
    float bv[4] = {bs.x, bs.y, bs.z, bs.w};
    #pragma unroll
    for (int qtL = 0; qtL < 2; ++qtL) {
      int qg = qblk + (wave * 2 + qtL) * 16 + lm;
      u16* Wp = W + ((size_t)b * NN_ + qg) * 64 + e0;
      uint2 wo = wres[qtL][et];
      float wv[4] = {bf2f((u16)(wo.x & 0xffff)), bf2f((u16)(wo.x >> 16)),
                     bf2f((u16)(wo.y & 0xffff)), bf2f((u16)(wo.y >> 16))};
      float o[4];
      #pragma unroll
      for (int r = 0; r < 4; ++r) {
        float res = use_norm ? fmaxf(fmaf(wv[r], scn[et][r], shn[et][r]), 0.f) : wv[r];
        float val = acc[qtL][et][r] + bv[r] + res;
        o[r] = val;
        s1[et][r] += val;
        s2[et][r] = fmaf(val, val, s2[et][r]);
      }
      uint2 ov;
      ov.x = pack2(o[0], o[1]);
      ov.y = pack2(o[2], o[3]);
      *(uint2*)Wp = ov;
    }
  }

  // wave-local reduce over lm, then block partial write (no atomics)
  #pragma unroll
  for (int et = 0; et < 4; ++et)
    #pragma unroll
    for (int r = 0; r < 4; ++r) {
      float a = s1[et][r], c = s2[et][r];
      a += __shfl_xor(a, 1, 64); a += __shfl_xor(a, 2, 64);
      a += __shfl_xor(a, 4, 64); a += __shfl_xor(a, 8, 64);
      c += __shfl_xor(c, 1, 64); c += __shfl_xor(c, 2, 64);
      c += __shfl_xor(c, 4, 64); c += __shfl_xor(c, 8, 64);
      if (lm == 0) {
        int e = et * 16 + lg * 4 + r;
        red[wave][e]      = a;
        red[wave][64 + e] = c;
      }
    }
  __syncthreads();
  if (tid < 128)
    pst[((size_t)b * 144 + qi) * 128 + tid] = red[0][tid] + red[1][tid];
}

// ---------------- pooling (W bf16; reduces stat partials itself) ----------------
__launch_bounds__(256)
__global__ void k_pool(const u16* __restrict__ W,
                       const float* __restrict__ pst,
                       const float* __restrict__ gml, const float* __restrict__ btl,
                       const float* __restrict__ pw, const float* __restrict__ pb,
                       float* __restrict__ out)
{
  __shared__ float nsS[128];
  const int b = blockIdx.x / 24;
  const int chunk = blockIdx.x % 24;
  const int tid = threadIdx.x;
  if (tid < 128) {
    const float* p = pst + ((size_t)b * 144) * 128 + tid;
    float a0 = 0.f, a1 = 0.f, a2 = 0.f, a3 = 0.f;
    for (int i = 0; i < 144; i += 4) {
      a0 += p[(size_t)i * 128];
      a1 += p[(size_t)(i + 1) * 128];
      a2 += p[(size_t)(i + 2) * 128];
      a3 += p[(size_t)(i + 3) * 128];
    }
    nsS[tid] = (a0 + a1) + (a2 + a3);
  }
  __syncthreads();
  const int e = tid & 63;
  float S1 = nsS[e], S2 = nsS[64 + e];
  float mu = S1 * INV_NN;
  float var = fmaf(S2, INV_NN, -mu * mu);
  float rsig = rsqrtf(var + EPS_);
  float scl = gml[e] * rsig;
  float shf = fmaf(-mu, scl, btl[e]);
  float pwv = pw[e];
  const u16* base = W + (size_t)b * NN_ * 64 + chunk * 24576;
  float s = 0.f;
  for (int k = 0; k < 96; k++) {
    float w = bf2f(base[k * 256 + tid]);
    s += fmaxf(fmaf(w, scl, shf), 0.f) * pwv;
  }
  for (int o = 32; o; o >>= 1) s += __shfl_down(s, o, 64);
  __shared__ float rs[4];
  if ((tid & 63) == 0) rs[tid >> 6] = s;
  __syncthreads();
  if (tid == 0) {
    float t = rs[0] + rs[1] + rs[2] + rs[3];
    if (chunk == 0) t += pb[0];
    atomicAdd(&out[b], t);
  }
}

extern "C" void kernel_launch(void* const* d_in, const int* in_sizes, int n_in,
                              void* d_out, int out_size, void* d_ws, size_t ws_size,
                              hipStream_t stream) {
  const int*   x    = (const int*)d_in[0];
  const int*   ei   = (const int*)d_in[1];
  const int*   ea   = (const int*)d_in[2];
  const float* nemb = (const float*)d_in[3];
  const float* eemb = (const float*)d_in[4];
  const float* W1   = (const float*)d_in[5];
  const float* b1   = (const float*)d_in[6];
  const float* W2   = (const float*)d_in[7];
  const float* b2   = (const float*)d_in[8];
  const float* Wm   = (const float*)d_in[9];
  const float* bm   = (const float*)d_in[10];
  const float* gm   = (const float*)d_in[11];
  const float* bt   = (const float*)d_in[12];
  const float* pw   = (const float*)d_in[13];
  const float* pb   = (const float*)d_in[14];

  char* ws = (char*)d_ws;
  const size_t OFF_A  = 0;                    // int[BNN]            1,179,648
  const size_t OFF_W  = 1179648;              // bf16[BNN*64]       37,748,736
  const size_t OFF_H1 = 38928384;             // bf16[64B][NN]      37,748,736
  const size_t OFF_G2 = 76677120;             // bf16[64B][NN]      37,748,736
  const size_t OFF_M  = 114425856;            // bf16[64B][NN]      37,748,736
  const size_t OFF_PS = 152174592;            // f32[32][144][128]   2,359,296
  const size_t OFF_NF = 154533888;            // f32[32][64][2]         16,384
  const size_t OFF_WT = 154550272;            // bf16[15][64][64]      122,880
  const size_t NEED   = OFF_WT + 122880;
  if (ws_size < NEED) return;

  int*   A     = (int*)(ws + OFF_A);
  u16*   W     = (u16*)(ws + OFF_W);
  u16*   h1    = (u16*)(ws + OFF_H1);
  u16*   g2n   = (u16*)(ws + OFF_G2);
  u16*   M     = (u16*)(ws + OFF_M);
  float* pst   = (float*)(ws + OFF_PS);
  float* nsF   = (float*)(ws + OFF_NF);
  u16*   WT    = (u16*)(ws + OFF_WT);
  float* out   = (float*)d_out;

  hipMemsetAsync(A, 0, 1179648, stream);
  hipMemsetAsync(out, 0, 32 * sizeof(float), stream);

  k_prep<<<240, 256, 0, stream>>>(W1, W2, Wm, WT);
  k_scatter<<<96, 256, 0, stream>>>(ei, ea, A);
  k_winit<<<18432, 256, 0, stream>>>(x, A, nemb, eemb, W);

  for (int l = 0; l < L_; l++) {
    int un = (l > 0);
    const float* gml = un ? gm + (l - 1) * 64 : gm;
    const float* btl = un ? bt + (l - 1) * 64 : bt;
    k_lin2<<<1152, 256, 0, stream>>>(W, WT + (l * 3 + 0) * 4096, WT + (l * 3 + 1) * 4096,
                                     b1 + l * 64, b2 + l * 64, A, pst, gml, btl, nsF,
                                     un, h1, g2n);
    k_einsum<<<2048, 256, 0, stream>>>(h1, g2n, M);
    k_update<<<4608, 128, 0, stream>>>(M, WT + (l * 3 + 2) * 4096, bm + l * 64, W,
                                       nsF, un, pst);
  }
  k_pool<<<768, 256, 0, stream>>>(W, pst, gm + 4 * 64, bt + 4 * 64, pw, pb, out);
}